// Round 16
// baseline (548.140 us; speedup 1.0000x reference)
//
#include <hip/hip_runtime.h>
#include <math.h>

// ---------------- problem constants ----------------
#define BB    32
#define C_IN  3
#define H0    256
#define W0    256
#define C1    32
#define H1    128
#define W1    128
#define C2    64
#define H2    64
#define W2    64
#define HW2   (H2*W2)     // 4096
#define N_EMB 512
#define E_DIM 64
#define NZ    (BB*C2*HW2) // 8388608
#define NPX   (BB*HW2)    // 131072 pixels in VQ

typedef unsigned short u16;
typedef unsigned int   uint;
typedef __attribute__((ext_vector_type(8))) short short8;
typedef __attribute__((ext_vector_type(4))) float f32x4;

__device__ inline u16 f2bf(float f) {
    uint u = __builtin_bit_cast(uint, f);
    u += 0x7FFF + ((u >> 16) & 1);          // RNE
    return (u16)(u >> 16);
}
__device__ inline float bf2f(u16 h) {
    uint u = (uint)h << 16;
    return __builtin_bit_cast(float, u);
}
__device__ inline f32x4 mfma16(short8 a, short8 b, f32x4 c) {
    return __builtin_amdgcn_mfma_f32_16x16x32_bf16(a, b, c, 0, 0, 0);
}
// XOR-swizzle for LDS row-major weight tiles (rows = 1<<RS bytes)
template<int RS>
__device__ inline int swz(int off) { return off ^ (((off >> RS) & 7) << 4); }

// ---- zero the halo border of an NHWC padded buffer (interior at (1,1)) ----
template<int C, int HP, int WP, int H, int W>
__global__ __launch_bounds__(256) void border_zero(u16* buf, int nimg) {
    int t = blockIdx.x * 256 + threadIdx.x;
    if (t >= nimg * HP * WP) return;
    int x = t % WP, y = (t / WP) % HP;
    if (y >= 1 && y < 1 + H && x >= 1 && x < 1 + W) return;
    uint4 z4; z4.x = 0; z4.y = 0; z4.z = 0; z4.w = 0;
    uint4* p = (uint4*)(buf + (size_t)t * C);
    #pragma unroll
    for (int i = 0; i < C / 8; ++i) p[i] = z4;
}

// ---- weight prep: deconv (CI,CO,4,4) fp32 -> bf16 [cls][oc][t*CI+ic] ----
template<int CI, int CO>
__global__ __launch_bounds__(256) void wt_deconv(const float* __restrict__ w,
        u16* __restrict__ wb) {
    int i = blockIdx.x * 256 + threadIdx.x;
    if (i >= 4 * CO * 4 * CI) return;
    int ic  = i % CI;
    int t   = (i / CI) & 3;
    int oc  = (i / (CI * 4)) % CO;
    int cls = i / (CI * 4 * CO);
    int py = cls >> 1, px = cls & 1, ty = t >> 1, tx = t & 1;
    int ky = py ? (ty ? 0 : 2) : (ty ? 3 : 1);
    int kx = px ? (tx ? 0 : 2) : (tx ? 3 : 1);
    wb[i] = f2bf(w[(((size_t)ic * CO + oc) * 4 + ky) * 4 + kx]);
}

// ---- weight prep: conv2 (64,32,4,4) fp32 -> bf16 [oc][tap*32+ic] ----
__global__ __launch_bounds__(256) void wt_conv2(const float* __restrict__ w,
        u16* __restrict__ wb) {
    int i = blockIdx.x * 256 + threadIdx.x;
    if (i >= 64 * 512) return;
    int ic = i & 31;
    int k  = (i >> 5) & 15;
    int oc = i >> 9;
    wb[i] = f2bf(w[(size_t)(oc * 32 + ic) * 16 + k]);
}

// ---- weight prep: conv3 (3,32,3,3) fp32 -> split-bf16 [hi/lo][oc16][tap*32+ic]
__global__ __launch_bounds__(256) void wt_conv3(const float* __restrict__ w,
        u16* __restrict__ wk) {
    int i = blockIdx.x * 256 + threadIdx.x;
    if (i >= 16 * 288) return;
    int ic = i & 31;
    int k  = (i / 32) % 9;
    int oc = i / 288;
    float hi = 0.f, lo = 0.f;
    if (oc < 3) {
        float v = w[(size_t)(oc * 32 + ic) * 9 + k];
        hi = bf2f(f2bf(v));
        lo = v - hi;
    }
    wk[i]            = f2bf(hi);
    wk[i + 16 * 288] = f2bf(lo);
}

// ---- emb prep: fp32 (512,64) -> split-bf16 tables ehi/elo [e][c] ----
__global__ __launch_bounds__(256) void wt_emb(const float* __restrict__ emb,
        u16* __restrict__ ehi, u16* __restrict__ elo) {
    int i = blockIdx.x * 256 + threadIdx.x;      // 32768
    float v = emb[i];
    u16 h = f2bf(v);
    ehi[i] = h;
    elo[i] = f2bf(v - bf2f(h));
}

// ---- conv1: 3->32, k4 s2 p1, ReLU; out = NHWC bf16 padded (131x131) ----
__global__ __launch_bounds__(256) void conv1_kernel(const float* __restrict__ x,
        const float* __restrict__ w, const float* __restrict__ bias,
        u16* __restrict__ out) {
    int t = blockIdx.x * 256 + threadIdx.x;           // 32*128*128
    int ox = t & (W1 - 1);
    int oy = (t >> 7) & (H1 - 1);
    int b  = t >> 14;
    const float* xb = x + (size_t)b * (C_IN * H0 * W0);
    float v[48];
    #pragma unroll
    for (int ic = 0; ic < 3; ++ic)
        #pragma unroll
        for (int dy = 0; dy < 4; ++dy) {
            int iy = oy * 2 - 1 + dy;
            #pragma unroll
            for (int dx = 0; dx < 4; ++dx) {
                int ix = ox * 2 - 1 + dx;
                float val = 0.f;
                if ((unsigned)iy < H0 && (unsigned)ix < W0)
                    val = xb[((size_t)ic * H0 + iy) * W0 + ix];
                v[(ic * 4 + dy) * 4 + dx] = val;
            }
        }
    u16 h[32];
    #pragma unroll
    for (int oc = 0; oc < C1; ++oc) {
        float a = bias[oc];
        #pragma unroll
        for (int k = 0; k < 48; ++k) a = fmaf(v[k], w[oc * 48 + k], a);
        h[oc] = f2bf(fmaxf(a, 0.f));
    }
    uint4* dst = (uint4*)(out + ((size_t)(b * 131 + oy + 1) * 131 + ox + 1) * 32);
    #pragma unroll
    for (int i = 0; i < 4; ++i) {
        uint4 u;
        u.x = (uint)h[i*8+0] | ((uint)h[i*8+1] << 16);
        u.y = (uint)h[i*8+2] | ((uint)h[i*8+3] << 16);
        u.z = (uint)h[i*8+4] | ((uint)h[i*8+5] << 16);
        u.w = (uint)h[i*8+6] | ((uint)h[i*8+7] << 16);
        dst[i] = u;
    }
}

// ---- conv2 via MFMA + LDS weights: 32->64 k4 s2; oc-half in bit 3 (XCD) ----
__global__ __launch_bounds__(256) void conv2_mfma(const u16* __restrict__ z1p,
        const u16* __restrict__ wb, const float* __restrict__ bias,
        float* __restrict__ z) {
    __shared__ u16 wlds[32 * 512];                    // 32 KB: 32 oc x 512 K
    int xcd = blockIdx.x & 7;
    int oh  = (blockIdx.x >> 3) & 1;
    int bx  = (blockIdx.x >> 4) * 8 + xcd;
    for (int j = threadIdx.x; j < 2048; j += 256) {   // 2048 x 16B
        int u = j * 8;
        int byteoff = swz<10>(u * 2);
        *(uint4*)((char*)wlds + byteoff) =
            *(const uint4*)(wb + (size_t)(oh * 32) * 512 + u);
    }
    __syncthreads();
    int wid = threadIdx.x >> 6, lane = threadIdx.x & 63;
    int m0 = bx * 128 + wid * 32;                     // 32 pixels per wave
    int b  = m0 >> 12;
    int y  = (m0 >> 6) & 63;
    int x0 = m0 & 63;
    int l15 = lane & 15, lk = lane >> 4;
    f32x4 acc[2][2] = {};
    int xA = x0 + l15, xB = x0 + 16 + l15;
    for (int ks = 0; ks < 16; ++ks) {
        int dy = ks >> 2, dx = ks & 3;
        int rb = (b * 131 + 2 * y + dy) * 131;
        short8 fbA = *(const short8*)(z1p + ((size_t)(rb + 2 * xA + dx)) * 32 + lk * 8);
        short8 fbB = *(const short8*)(z1p + ((size_t)(rb + 2 * xB + dx)) * 32 + lk * 8);
        #pragma unroll
        for (int f = 0; f < 2; ++f) {
            int byteoff = swz<10>((f * 16 + l15) * 1024 + ks * 64 + lk * 16);
            short8 fa = *(const short8*)((const char*)wlds + byteoff);
            acc[0][f] = mfma16(fa, fbA, acc[0][f]);
            acc[1][f] = mfma16(fa, fbB, acc[1][f]);
        }
    }
    #pragma unroll
    for (int p = 0; p < 2; ++p) {
        int pix = m0 + p * 16 + l15;
        #pragma unroll
        for (int f = 0; f < 2; ++f) {
            int oc0 = oh * 32 + f * 16 + lk * 4;
            float4 bi = *(const float4*)(bias + oc0);
            float4 r;
            r.x = fmaxf(acc[p][f][0] + bi.x, 0.f);
            r.y = fmaxf(acc[p][f][1] + bi.y, 0.f);
            r.z = fmaxf(acc[p][f][2] + bi.z, 0.f);
            r.w = fmaxf(acc[p][f][3] + bi.w, 0.f);
            *(float4*)(z + (size_t)pix * 64 + oc0) = r;
        }
    }
}

// ---------------- embedding squared norms ----------------
__global__ void e2_kernel(const float* __restrict__ emb, float* __restrict__ e2) {
    int e = blockIdx.x * 64 + threadIdx.x;
    float s = 0.f;
    #pragma unroll
    for (int c = 0; c < E_DIM; ++c) {
        float v = emb[(size_t)e * E_DIM + c];
        s = fmaf(v, v, s);
    }
    e2[e] = s;
}

// ---- VQ via MFMA (split-bf16), running argmin w/ first-min tie rule ----
__global__ __launch_bounds__(256) void vq_mfma(const float* __restrict__ zf,
        const u16* __restrict__ ehi, const u16* __restrict__ elo,
        const float* __restrict__ e2, const float* __restrict__ emb,
        float* __restrict__ q) {
    int wid = threadIdx.x >> 6, lane = threadIdx.x & 63;
    int l15 = lane & 15, lk = lane >> 4;
    int m0 = (blockIdx.x * 4 + wid) * 32;
    short8 zh[2][2], zl[2][2];                 // [half][ks]
    #pragma unroll
    for (int h = 0; h < 2; ++h) {
        int px = m0 + h * 16 + l15;
        const float4* zp = (const float4*)(zf + (size_t)px * 64);
        #pragma unroll
        for (int ks = 0; ks < 2; ++ks) {
            short8 hh, ll;
            #pragma unroll
            for (int j2 = 0; j2 < 2; ++j2) {
                float4 v4 = zp[ks * 8 + lk * 2 + j2];
                float vv[4] = {v4.x, v4.y, v4.z, v4.w};
                #pragma unroll
                for (int j = 0; j < 4; ++j) {
                    u16 hb = f2bf(vv[j]);
                    hh[j2 * 4 + j] = (short)hb;
                    ll[j2 * 4 + j] = (short)f2bf(vv[j] - bf2f(hb));
                }
            }
            zh[h][ks] = hh;
            zl[h][ks] = ll;
        }
    }
    float bs[2] = {3.4e38f, 3.4e38f};
    int   bi[2] = {0, 0};
    for (int tile = 0; tile < 32; ++tile) {
        short8 fh[2], fl[2];
        #pragma unroll
        for (int ks = 0; ks < 2; ++ks) {
            fh[ks] = *(const short8*)(ehi + (size_t)(tile * 16 + l15) * 64 + ks * 32 + lk * 8);
            fl[ks] = *(const short8*)(elo + (size_t)(tile * 16 + l15) * 64 + ks * 32 + lk * 8);
        }
        float4 e2v = *(const float4*)(e2 + tile * 16 + lk * 4);
        float ee[4] = {e2v.x, e2v.y, e2v.z, e2v.w};
        #pragma unroll
        for (int h = 0; h < 2; ++h) {
            f32x4 acc = {};
            #pragma unroll
            for (int ks = 0; ks < 2; ++ks) {
                acc = mfma16(fh[ks], zh[h][ks], acc);
                acc = mfma16(fl[ks], zh[h][ks], acc);
                acc = mfma16(fh[ks], zl[h][ks], acc);
            }
            #pragma unroll
            for (int r = 0; r < 4; ++r) {
                float sc = ee[r] - 2.f * acc[r];
                int ei = tile * 16 + lk * 4 + r;
                if (sc < bs[h]) { bs[h] = sc; bi[h] = ei; }
            }
        }
    }
    #pragma unroll
    for (int h = 0; h < 2; ++h) {
        #pragma unroll
        for (int off = 16; off < 64; off <<= 1) {
            float s2 = __shfl_xor(bs[h], off, 64);
            int   i2 = __shfl_xor(bi[h], off, 64);
            if (s2 < bs[h] || (s2 == bs[h] && i2 < bi[h])) { bs[h] = s2; bi[h] = i2; }
        }
    }
    #pragma unroll
    for (int h = 0; h < 2; ++h) {
        for (int p = 0; p < 16; ++p) {
            int idx = __shfl(bi[h], p, 64);
            int px  = m0 + h * 16 + p;
            q[(size_t)px * 64 + lane] = emb[(size_t)idx * 64 + lane];
        }
    }
}

// ---- loss with faithful NCHW pairing: q_flat[i] vs z_nchw(i); z stored NHWC ----
__global__ __launch_bounds__(256) void loss_tr(const float* __restrict__ q,
        const float* __restrict__ z, float* __restrict__ part) {
    __shared__ float zt[64 * 65];
    int bh = blockIdx.x;                       // b*64 + h
    size_t zbase = (size_t)bh * 4096;
    for (int j = threadIdx.x; j < 4096; j += 256) {
        int w = j >> 6, c = j & 63;
        zt[w * 65 + c] = z[zbase + j];
    }
    __syncthreads();
    int b = bh >> 6, h = bh & 63;
    int w = threadIdx.x & 63;
    float s = 0.f;
    #pragma unroll
    for (int k = 0; k < 16; ++k) {
        int cc = (threadIdx.x >> 6) + k * 4;
        float qv = q[(size_t)b * 262144 + (size_t)cc * 4096 + h * 64 + w];
        float d = qv - zt[w * 65 + cc];
        s = fmaf(d, d, s);
    }
    #pragma unroll
    for (int off = 32; off; off >>= 1) s += __shfl_down(s, off, 64);
    __shared__ float red[4];
    int lane = threadIdx.x & 63, wid = threadIdx.x >> 6;
    if (lane == 0) red[wid] = s;
    __syncthreads();
    if (threadIdx.x == 0) part[blockIdx.x] = (red[0] + red[1]) + (red[2] + red[3]);
}

__global__ __launch_bounds__(256) void loss_final(const float* __restrict__ part,
        float* __restrict__ loss, float scale) {
    float s = 0.f;
    for (int i = threadIdx.x; i < 2048; i += 256) s += part[i];
    #pragma unroll
    for (int off = 32; off; off >>= 1) s += __shfl_down(s, off, 64);
    __shared__ float red[4];
    int lane = threadIdx.x & 63, wid = threadIdx.x >> 6;
    if (lane == 0) red[wid] = s;
    __syncthreads();
    if (threadIdx.x == 0)
        *loss = ((red[0] + red[1]) + (red[2] + red[3])) * scale;
}

// ---- q (NCHW view of q_flat) -> dq NHWC bf16 padded 66x66 ----
__global__ __launch_bounds__(256) void q_transpose(const float* __restrict__ q,
        u16* __restrict__ dq) {
    int t = blockIdx.x * 256 + threadIdx.x;    // 131072
    int x = t & 63, y = (t >> 6) & 63, b = t >> 12;
    const float* src = q + (size_t)b * 262144 + y * 64 + x;
    u16 h[64];
    #pragma unroll
    for (int ic = 0; ic < 64; ++ic) h[ic] = f2bf(src[(size_t)ic * 4096]);
    uint4* dst = (uint4*)(dq + ((size_t)(b * 66 + y + 1) * 66 + x + 1) * 64);
    #pragma unroll
    for (int i = 0; i < 8; ++i) {
        uint4 u;
        u.x = (uint)h[i*8+0] | ((uint)h[i*8+1] << 16);
        u.y = (uint)h[i*8+2] | ((uint)h[i*8+3] << 16);
        u.z = (uint)h[i*8+4] | ((uint)h[i*8+5] << 16);
        u.w = (uint)h[i*8+6] | ((uint)h[i*8+7] << 16);
        dst[i] = u;
    }
}

// ---- deconv1 k4 s2 p1 via MFMA + LDS weights (variant bits above XCD) ----
template<int CO, int NOC, int PT, int HI, int WI, int NYB>
__global__ __launch_bounds__(256) void deconv_lds(const u16* __restrict__ in,
        const u16* __restrict__ wb, const float* __restrict__ bias,
        u16* __restrict__ out) {
    constexpr int HPI = HI + 2, WPI = WI + 2;
    constexpr int HPO = 2 * HI + 2, WPO = 2 * WI + 2;
    constexpr int NF = NOC / 16;
    constexpr int NW16 = 2 * NOC * 256;               // u16 count in LDS
    constexpr int LOG2NYB = (NYB == 4) ? 2 : 1;
    __shared__ u16 wlds[NW16];                        // 32 KB at NOC=32
    int xcd = blockIdx.x & 7;
    int byv = (blockIdx.x >> 3) & (NYB - 1);
    int bx  = (blockIdx.x >> (3 + LOG2NYB)) * 8 + xcd;
    int py = byv & 1;
    int oh = byv >> 1;
    int oc_base = oh * NOC;
    for (int j = threadIdx.x; j < NW16 / 8; j += 256) {
        int u = j * 8;
        int clsl = u / (NOC * 256);
        int rem = u - clsl * (NOC * 256);
        int byteoff = swz<9>(u * 2);
        *(uint4*)((char*)wlds + byteoff) = *(const uint4*)(wb
            + ((size_t)((py * 2 + clsl) * CO + oc_base)) * 256 + rem);
    }
    __syncthreads();
    int sy = py ? 1 : -1;
    int wid = threadIdx.x >> 6, lane = threadIdx.x & 63;
    int m0 = bx * (PT * 64) + wid * (PT * 16);
    int b = m0 / (HI * WI);
    int rem0 = m0 % (HI * WI);
    int y = rem0 / WI, x0 = rem0 % WI;
    int l15 = lane & 15, lk = lane >> 4;

    short8 fbuf[2][3][2][PT];                  // [idy][dx+1][ks][p]
    #pragma unroll
    for (int idy = 0; idy < 2; ++idy) {
        int dy = idy ? sy : 0;
        int rb = (b * HPI + y + dy + 1) * WPI;
        #pragma unroll
        for (int idx = 0; idx < 3; ++idx)
            #pragma unroll
            for (int ks = 0; ks < 2; ++ks)
                #pragma unroll
                for (int p = 0; p < PT; ++p)
                    fbuf[idy][idx][ks][p] = *(const short8*)(in
                        + (size_t)(rb + x0 + p * 16 + l15 + idx) * 64
                        + ks * 32 + lk * 8);
    }

    f32x4 acc[PT][2][NF] = {};
    #pragma unroll
    for (int idy = 0; idy < 2; ++idy)
        #pragma unroll
        for (int idx = 0; idx < 3; ++idx) {
            int dx = idx - 1;
            #pragma unroll
            for (int ks = 0; ks < 2; ++ks)
                #pragma unroll
                for (int pxc = 0; pxc < 2; ++pxc) {
                    int sx = pxc ? 1 : -1;
                    if (!(dx == 0 || dx == sx)) continue;   // compile-time pruned
                    int t = 2 * (idy != 0) + (dx != 0);
                    #pragma unroll
                    for (int f = 0; f < NF; ++f) {
                        int row = pxc * NOC + f * 16 + l15;
                        int byteoff = swz<9>(row * 512 + (t * 2 + ks) * 64 + lk * 16);
                        short8 fa = *(const short8*)((const char*)wlds + byteoff);
                        #pragma unroll
                        for (int p = 0; p < PT; ++p)
                            acc[p][pxc][f] = mfma16(fa, fbuf[idy][idx][ks][p],
                                                    acc[p][pxc][f]);
                    }
                }
        }

    #pragma unroll
    for (int p = 0; p < PT; ++p) {
        int x = x0 + p * 16 + l15;
        #pragma unroll
        for (int pxc = 0; pxc < 2; ++pxc) {
            int oy = 2 * y + py + 1, ox = 2 * x + pxc + 1;
            size_t po = ((size_t)(b * HPO + oy) * WPO + ox) * CO;
            #pragma unroll
            for (int f = 0; f < NF; ++f) {
                int oc0 = oc_base + f * 16 + lk * 4;
                float4 bi = *(const float4*)(bias + oc0);
                float r0 = fmaxf(acc[p][pxc][f][0] + bi.x, 0.f);
                float r1 = fmaxf(acc[p][pxc][f][1] + bi.y, 0.f);
                float r2 = fmaxf(acc[p][pxc][f][2] + bi.z, 0.f);
                float r3 = fmaxf(acc[p][pxc][f][3] + bi.w, 0.f);
                uint2 uu;
                uu.x = (uint)f2bf(r0) | ((uint)f2bf(r1) << 16);
                uu.y = (uint)f2bf(r2) | ((uint)f2bf(r3) << 16);
                *(uint2*)(out + po + oc0) = uu;
            }
        }
    }
}

// ---- deconv2 (64->32, 128x128): input in LDS, weights in VGPR, one class ----
// Block = (b, y, py, pxc); py,pxc in bits 3-4 (above XCD round-robin) so the 4
// variants of one row share an XCD L2. LDS = input only (33KB) -> 4 blocks/CU;
// weights = 16 short8/lane in registers -> zero weight ds_reads.
__global__ __launch_bounds__(256) void deconv2_stage(const u16* __restrict__ in,
        const u16* __restrict__ wb, const float* __restrict__ bias,
        u16* __restrict__ out) {
    __shared__ u16 ilds[2 * 130 * 64];         // 33,280 B
    int xcd = blockIdx.x & 7;
    int pv  = (blockIdx.x >> 3) & 3;
    int bx  = (blockIdx.x >> 5) * 8 + xcd;     // 0..4095 = b*128 + y
    int pxc = pv & 1, py = pv >> 1;
    int b = bx >> 7, y = bx & 127;
    int sy = py ? 1 : -1, sx = pxc ? 1 : -1;
    int cls = py * 2 + pxc;
    int lane = threadIdx.x & 63;
    int l15 = lane & 15, lk = lane >> 4;

    // weight fragments in registers: [t][ks][f]
    short8 wfrag[4][2][2];
    #pragma unroll
    for (int t = 0; t < 4; ++t)
        #pragma unroll
        for (int ks = 0; ks < 2; ++ks)
            #pragma unroll
            for (int f = 0; f < 2; ++f)
                wfrag[t][ks][f] = *(const short8*)(wb
                    + (size_t)(cls * 32 + f * 16 + l15) * 256
                    + (t * 2 + ks) * 32 + lk * 8);

    // stage input rows y and y+sy (padded +1), XOR-swizzled
    int rowg0 = (b * 130 + y + 1) * 130;
    int rowg1 = (b * 130 + y + sy + 1) * 130;
    for (int j = threadIdx.x; j < 2080; j += 256) {
        int row = (j >= 1040);
        int rem = j - row * 1040;
        int px = rem >> 3, c16 = rem & 7;
        int rg = row ? rowg1 : rowg0;
        uint4 v = *(const uint4*)(in + (size_t)(rg + px) * 64 + c16 * 8);
        int lbyte = (j * 16) ^ ((px & 7) << 4);
        *(uint4*)((char*)ilds + lbyte) = v;
    }
    __syncthreads();

    int wid = threadIdx.x >> 6;
    int xw = wid * 32;                         // wave's first local px
    f32x4 acc[2][2] = {};                      // [p][f]
    #pragma unroll
    for (int idy = 0; idy < 2; ++idy)
        #pragma unroll
        for (int idx = 0; idx < 3; ++idx) {
            int dx = idx - 1;
            if (!(dx == 0 || dx == sx)) continue;   // block-uniform branch
            int t = 2 * (idy != 0) + (dx != 0);
            #pragma unroll
            for (int ks = 0; ks < 2; ++ks) {
                short8 fb[2];
                #pragma unroll
                for (int p = 0; p < 2; ++p) {
                    int pxl = xw + p * 16 + l15 + idx;   // 0..129
                    int lbyte = ((idy * 130 + pxl) * 128 + ks * 64 + lk * 16)
                                ^ ((pxl & 7) << 4);
                    fb[p] = *(const short8*)((const char*)ilds + lbyte);
                }
                #pragma unroll
                for (int f = 0; f < 2; ++f)
                    #pragma unroll
                    for (int p = 0; p < 2; ++p)
                        acc[p][f] = mfma16(wfrag[t][ks][f], fb[p], acc[p][f]);
            }
        }

    #pragma unroll
    for (int p = 0; p < 2; ++p) {
        int x = xw + p * 16 + l15;
        int oy = 2 * y + py + 1, ox = 2 * x + pxc + 1;
        size_t po = ((size_t)(b * 258 + oy) * 258 + ox) * 32;
        #pragma unroll
        for (int f = 0; f < 2; ++f) {
            int oc0 = f * 16 + lk * 4;
            float4 bi = *(const float4*)(bias + oc0);
            float r0 = fmaxf(acc[p][f][0] + bi.x, 0.f);
            float r1 = fmaxf(acc[p][f][1] + bi.y, 0.f);
            float r2 = fmaxf(acc[p][f][2] + bi.z, 0.f);
            float r3 = fmaxf(acc[p][f][3] + bi.w, 0.f);
            uint2 uu;
            uu.x = (uint)f2bf(r0) | ((uint)f2bf(r1) << 16);
            uu.y = (uint)f2bf(r2) | ((uint)f2bf(r3) << 16);
            *(uint2*)(out + po + oc0) = uu;
        }
    }
}

// ---- conv3 via MFMA: 32->3 k3 s1 p1 + sigmoid; hoisted fb, LDS weights ----
__global__ __launch_bounds__(256) void conv3_mfma(const u16* __restrict__ in,
        const u16* __restrict__ wk, const float* __restrict__ bias,
        float* __restrict__ out) {
    __shared__ u16 walds[16 * 288 * 2];        // 18432 B, swizzled
    for (int j = threadIdx.x; j < 1152; j += 256) {
        int u = j * 8;
        *(uint4*)((char*)walds + swz<9>(u * 2)) = *(const uint4*)(wk + u);
    }
    __syncthreads();
    int wid = threadIdx.x >> 6, lane = threadIdx.x & 63;
    int m0 = (blockIdx.x * 4 + wid) * 16;      // 16 px per wave
    int b   = m0 >> 16;
    int rem = m0 & 65535;
    int y   = rem >> 8;
    int x0  = rem & 255;
    int l15 = lane & 15, lk = lane >> 4;
    short8 fb[3][3];
    #pragma unroll
    for (int dy = 0; dy < 3; ++dy) {
        int rb = (b * 258 + y + dy) * 258;
        #pragma unroll
        for (int dx = 0; dx < 3; ++dx)
            fb[dy][dx] = *(const short8*)(in + (size_t)(rb + x0 + l15 + dx) * 32 + lk * 8);
    }
    f32x4 acc = {};
    #pragma unroll
    for (int ks = 0; ks < 9; ++ks) {
        int base = (l15 * 288 + ks * 32 + lk * 8) * 2;
        short8 fah = *(const short8*)((const char*)walds + swz<9>(base));
        short8 fal = *(const short8*)((const char*)walds + swz<9>(base + 9216));
        acc = mfma16(fah, fb[ks / 3][ks % 3], acc);
        acc = mfma16(fal, fb[ks / 3][ks % 3], acc);
    }
    if (lk == 0) {
        int px = x0 + l15;
        float* ob = out + (size_t)b * 196608 + (size_t)y * 256 + px;
        ob[0]      = 1.f / (1.f + expf(-(acc[0] + bias[0])));
        ob[65536]  = 1.f / (1.f + expf(-(acc[1] + bias[1])));
        ob[131072] = 1.f / (1.f + expf(-(acc[2] + bias[2])));
    }
}

// ---------------- launch ----------------
extern "C" void kernel_launch(void* const* d_in, const int* in_sizes, int n_in,
                              void* d_out, int out_size, void* d_ws, size_t ws_size,
                              hipStream_t stream) {
    (void)in_sizes; (void)n_in; (void)out_size;
    const float* x   = (const float*)d_in[0];
    const float* e1w = (const float*)d_in[1];
    const float* e1b = (const float*)d_in[2];
    const float* e2w = (const float*)d_in[3];
    const float* e2b = (const float*)d_in[4];
    const float* emb = (const float*)d_in[5];
    const float* d1w = (const float*)d_in[6];
    const float* d1b = (const float*)d_in[7];
    const float* d2w = (const float*)d_in[8];
    const float* d2b = (const float*)d_in[9];
    const float* d3w = (const float*)d_in[10];
    const float* d3b = (const float*)d_in[11];

    float* out   = (float*)d_out;
    float* recon = out;                    // 6291456 floats
    float* loss  = out + 6291456;          // 1 float
    float* q     = out + 6291457;          // 8388608 floats (4B-aligned only)

    char* wsb = (char*)d_ws;
    u16*   wt1b = (u16*)(wsb + 0);         // 131072 B
    u16*   wt2b = (u16*)(wsb + 131072);    // 65536 B
    u16*   wc2b = (u16*)(wsb + 196608);    // 65536 B
    float* e2v  = (float*)(wsb + 262144);  // 512 f
    float* prt  = (float*)(wsb + 264192);  // 2048 f -> ends 272384
    u16*   wk3  = (u16*)(wsb + 272384);    // 18432 B -> ends 290816
    u16*   ehib = (u16*)(wsb + 290816);    // 65536 B
    u16*   elob = (u16*)(wsb + 356352);    // 65536 B -> ends 421888
    char*  big  = wsb + 524288;

    u16*   z1p = (u16*)big;                     // 35,145,728 B
    float* zf  = (float*)(big + 35145728);      // 33,554,432 B
    u16* dq = (u16*)big;                        // decoder reuse (z1p dead)

    size_t avail = ws_size > (size_t)524288 ? ws_size - 524288 : 0;
    int G = 32;
    while (G > 1 && (size_t)17842176 + (size_t)G * 6423296 > avail) G >>= 1;
    int ngrp = BB / G;
    u16* h1p = (u16*)(big + 17842176);
    u16* h2p = (u16*)(big + 17842176 + (size_t)G * 2163200);

    // weight prep
    wt_deconv<64, 64><<<256, 256, 0, stream>>>(d1w, wt1b);
    wt_deconv<64, 32><<<128, 256, 0, stream>>>(d2w, wt2b);
    wt_conv2<<<128, 256, 0, stream>>>(e2w, wc2b);
    wt_conv3<<<18, 256, 0, stream>>>(d3w, wk3);
    wt_emb<<<128, 256, 0, stream>>>(emb, ehib, elob);
    e2_kernel<<<8, 64, 0, stream>>>(emb, e2v);

    // encoder (full batch)
    border_zero<32, 131, 131, 128, 128><<<2146, 256, 0, stream>>>(z1p, 32);
    conv1_kernel<<<2048, 256, 0, stream>>>(x, e1w, e1b, z1p);
    conv2_mfma<<<2048, 256, 0, stream>>>(z1p, wc2b, e2b, zf);
    vq_mfma<<<1024, 256, 0, stream>>>(zf, ehib, elob, e2v, emb, q);
    loss_tr<<<2048, 256, 0, stream>>>(q, zf, prt);

    // decoder
    border_zero<64, 66, 66, 64, 64><<<545, 256, 0, stream>>>(dq, 32);
    q_transpose<<<512, 256, 0, stream>>>(q, dq);
    border_zero<64, 130, 130, 128, 128><<<(G * 16900 + 255) / 256, 256, 0, stream>>>(h1p, G);
    border_zero<32, 258, 258, 256, 256><<<(G * 66564 + 255) / 256, 256, 0, stream>>>(h2p, G);
    for (int g = 0; g < ngrp; ++g) {
        u16* dqg = dq + (size_t)g * G * 278784;
        // deconv1: 64->64, NOC=32, PT=2, 4 class-variants in bits 3-4
        deconv_lds<64, 32, 2, 64, 64, 4>
            <<<G * 32 * 4, 256, 0, stream>>>(dqg, wt1b, d1b, h1p);
        // deconv2: input-LDS + VGPR weights; (py,pxc) in bits 3-4
        deconv2_stage<<<G * 128 * 4, 256, 0, stream>>>(h1p, wt2b, d2b, h2p);
        conv3_mfma<<<G * 1024, 256, 0, stream>>>(h2p, wk3, d3b,
                                                 recon + (size_t)g * G * 196608);
    }
    loss_final<<<1, 256, 0, stream>>>(prt, loss, 1.25f / (float)NZ);
}

// Round 17
// 450.602 us; speedup vs baseline: 1.2165x; 1.2165x over previous
//
#include <hip/hip_runtime.h>
#include <math.h>

// ---------------- problem constants ----------------
#define BB    32
#define C_IN  3
#define H0    256
#define W0    256
#define C1    32
#define H1    128
#define W1    128
#define C2    64
#define H2    64
#define W2    64
#define HW2   (H2*W2)     // 4096
#define N_EMB 512
#define E_DIM 64
#define NZ    (BB*C2*HW2) // 8388608
#define NPX   (BB*HW2)    // 131072 pixels in VQ

typedef unsigned short u16;
typedef unsigned int   uint;
typedef __attribute__((ext_vector_type(8))) short short8;
typedef __attribute__((ext_vector_type(4))) float f32x4;

__device__ inline u16 f2bf(float f) {
    uint u = __builtin_bit_cast(uint, f);
    u += 0x7FFF + ((u >> 16) & 1);          // RNE
    return (u16)(u >> 16);
}
__device__ inline float bf2f(u16 h) {
    uint u = (uint)h << 16;
    return __builtin_bit_cast(float, u);
}
__device__ inline f32x4 mfma16(short8 a, short8 b, f32x4 c) {
    return __builtin_amdgcn_mfma_f32_16x16x32_bf16(a, b, c, 0, 0, 0);
}
// XOR-swizzle for LDS row-major weight tiles (rows = 1<<RS bytes)
template<int RS>
__device__ inline int swz(int off) { return off ^ (((off >> RS) & 7) << 4); }

// ---- zero the halo border of an NHWC padded buffer (interior at (1,1)) ----
template<int C, int HP, int WP, int H, int W>
__global__ __launch_bounds__(256) void border_zero(u16* buf, int nimg) {
    int t = blockIdx.x * 256 + threadIdx.x;
    if (t >= nimg * HP * WP) return;
    int x = t % WP, y = (t / WP) % HP;
    if (y >= 1 && y < 1 + H && x >= 1 && x < 1 + W) return;
    uint4 z4; z4.x = 0; z4.y = 0; z4.z = 0; z4.w = 0;
    uint4* p = (uint4*)(buf + (size_t)t * C);
    #pragma unroll
    for (int i = 0; i < C / 8; ++i) p[i] = z4;
}

// ---- weight prep: deconv (CI,CO,4,4) fp32 -> bf16 [cls][oc][t*CI+ic] ----
template<int CI, int CO>
__global__ __launch_bounds__(256) void wt_deconv(const float* __restrict__ w,
        u16* __restrict__ wb) {
    int i = blockIdx.x * 256 + threadIdx.x;
    if (i >= 4 * CO * 4 * CI) return;
    int ic  = i % CI;
    int t   = (i / CI) & 3;
    int oc  = (i / (CI * 4)) % CO;
    int cls = i / (CI * 4 * CO);
    int py = cls >> 1, px = cls & 1, ty = t >> 1, tx = t & 1;
    int ky = py ? (ty ? 0 : 2) : (ty ? 3 : 1);
    int kx = px ? (tx ? 0 : 2) : (tx ? 3 : 1);
    wb[i] = f2bf(w[(((size_t)ic * CO + oc) * 4 + ky) * 4 + kx]);
}

// ---- weight prep: conv2 (64,32,4,4) fp32 -> bf16 [oc][tap*32+ic] ----
__global__ __launch_bounds__(256) void wt_conv2(const float* __restrict__ w,
        u16* __restrict__ wb) {
    int i = blockIdx.x * 256 + threadIdx.x;
    if (i >= 64 * 512) return;
    int ic = i & 31;
    int k  = (i >> 5) & 15;
    int oc = i >> 9;
    wb[i] = f2bf(w[(size_t)(oc * 32 + ic) * 16 + k]);
}

// ---- weight prep: conv3 (3,32,3,3) fp32 -> split-bf16 [hi/lo][oc16][tap*32+ic]
__global__ __launch_bounds__(256) void wt_conv3(const float* __restrict__ w,
        u16* __restrict__ wk) {
    int i = blockIdx.x * 256 + threadIdx.x;
    if (i >= 16 * 288) return;
    int ic = i & 31;
    int k  = (i / 32) % 9;
    int oc = i / 288;
    float hi = 0.f, lo = 0.f;
    if (oc < 3) {
        float v = w[(size_t)(oc * 32 + ic) * 9 + k];
        hi = bf2f(f2bf(v));
        lo = v - hi;
    }
    wk[i]            = f2bf(hi);
    wk[i + 16 * 288] = f2bf(lo);
}

// ---- emb prep: fp32 (512,64) -> split-bf16 tables ehi/elo [e][c] ----
__global__ __launch_bounds__(256) void wt_emb(const float* __restrict__ emb,
        u16* __restrict__ ehi, u16* __restrict__ elo) {
    int i = blockIdx.x * 256 + threadIdx.x;      // 32768
    float v = emb[i];
    u16 h = f2bf(v);
    ehi[i] = h;
    elo[i] = f2bf(v - bf2f(h));
}

// ---- conv1: 3->32, k4 s2 p1, ReLU; out = NHWC bf16 padded (131x131) ----
__global__ __launch_bounds__(256) void conv1_kernel(const float* __restrict__ x,
        const float* __restrict__ w, const float* __restrict__ bias,
        u16* __restrict__ out) {
    int t = blockIdx.x * 256 + threadIdx.x;           // 32*128*128
    int ox = t & (W1 - 1);
    int oy = (t >> 7) & (H1 - 1);
    int b  = t >> 14;
    const float* xb = x + (size_t)b * (C_IN * H0 * W0);
    float v[48];
    #pragma unroll
    for (int ic = 0; ic < 3; ++ic)
        #pragma unroll
        for (int dy = 0; dy < 4; ++dy) {
            int iy = oy * 2 - 1 + dy;
            #pragma unroll
            for (int dx = 0; dx < 4; ++dx) {
                int ix = ox * 2 - 1 + dx;
                float val = 0.f;
                if ((unsigned)iy < H0 && (unsigned)ix < W0)
                    val = xb[((size_t)ic * H0 + iy) * W0 + ix];
                v[(ic * 4 + dy) * 4 + dx] = val;
            }
        }
    u16 h[32];
    #pragma unroll
    for (int oc = 0; oc < C1; ++oc) {
        float a = bias[oc];
        #pragma unroll
        for (int k = 0; k < 48; ++k) a = fmaf(v[k], w[oc * 48 + k], a);
        h[oc] = f2bf(fmaxf(a, 0.f));
    }
    uint4* dst = (uint4*)(out + ((size_t)(b * 131 + oy + 1) * 131 + ox + 1) * 32);
    #pragma unroll
    for (int i = 0; i < 4; ++i) {
        uint4 u;
        u.x = (uint)h[i*8+0] | ((uint)h[i*8+1] << 16);
        u.y = (uint)h[i*8+2] | ((uint)h[i*8+3] << 16);
        u.z = (uint)h[i*8+4] | ((uint)h[i*8+5] << 16);
        u.w = (uint)h[i*8+6] | ((uint)h[i*8+7] << 16);
        dst[i] = u;
    }
}

// ---- conv2 via MFMA + LDS weights: 32->64 k4 s2; oc-half in bit 3 (XCD) ----
__global__ __launch_bounds__(256) void conv2_mfma(const u16* __restrict__ z1p,
        const u16* __restrict__ wb, const float* __restrict__ bias,
        float* __restrict__ z) {
    __shared__ u16 wlds[32 * 512];                    // 32 KB: 32 oc x 512 K
    int xcd = blockIdx.x & 7;
    int oh  = (blockIdx.x >> 3) & 1;
    int bx  = (blockIdx.x >> 4) * 8 + xcd;
    for (int j = threadIdx.x; j < 2048; j += 256) {   // 2048 x 16B
        int u = j * 8;
        int byteoff = swz<10>(u * 2);
        *(uint4*)((char*)wlds + byteoff) =
            *(const uint4*)(wb + (size_t)(oh * 32) * 512 + u);
    }
    __syncthreads();
    int wid = threadIdx.x >> 6, lane = threadIdx.x & 63;
    int m0 = bx * 128 + wid * 32;                     // 32 pixels per wave
    int b  = m0 >> 12;
    int y  = (m0 >> 6) & 63;
    int x0 = m0 & 63;
    int l15 = lane & 15, lk = lane >> 4;
    f32x4 acc[2][2] = {};
    int xA = x0 + l15, xB = x0 + 16 + l15;
    for (int ks = 0; ks < 16; ++ks) {
        int dy = ks >> 2, dx = ks & 3;
        int rb = (b * 131 + 2 * y + dy) * 131;
        short8 fbA = *(const short8*)(z1p + ((size_t)(rb + 2 * xA + dx)) * 32 + lk * 8);
        short8 fbB = *(const short8*)(z1p + ((size_t)(rb + 2 * xB + dx)) * 32 + lk * 8);
        #pragma unroll
        for (int f = 0; f < 2; ++f) {
            int byteoff = swz<10>((f * 16 + l15) * 1024 + ks * 64 + lk * 16);
            short8 fa = *(const short8*)((const char*)wlds + byteoff);
            acc[0][f] = mfma16(fa, fbA, acc[0][f]);
            acc[1][f] = mfma16(fa, fbB, acc[1][f]);
        }
    }
    #pragma unroll
    for (int p = 0; p < 2; ++p) {
        int pix = m0 + p * 16 + l15;
        #pragma unroll
        for (int f = 0; f < 2; ++f) {
            int oc0 = oh * 32 + f * 16 + lk * 4;
            float4 bi = *(const float4*)(bias + oc0);
            float4 r;
            r.x = fmaxf(acc[p][f][0] + bi.x, 0.f);
            r.y = fmaxf(acc[p][f][1] + bi.y, 0.f);
            r.z = fmaxf(acc[p][f][2] + bi.z, 0.f);
            r.w = fmaxf(acc[p][f][3] + bi.w, 0.f);
            *(float4*)(z + (size_t)pix * 64 + oc0) = r;
        }
    }
}

// ---------------- embedding squared norms ----------------
__global__ void e2_kernel(const float* __restrict__ emb, float* __restrict__ e2) {
    int e = blockIdx.x * 64 + threadIdx.x;
    float s = 0.f;
    #pragma unroll
    for (int c = 0; c < E_DIM; ++c) {
        float v = emb[(size_t)e * E_DIM + c];
        s = fmaf(v, v, s);
    }
    e2[e] = s;
}

// ---- VQ via MFMA (split-bf16); gather writes BOTH q (fp32 flat) and
// dq (bf16 NHWC padded 66x66) — q_transpose fused away. ----
__global__ __launch_bounds__(256) void vq_mfma(const float* __restrict__ zf,
        const u16* __restrict__ ehi, const u16* __restrict__ elo,
        const float* __restrict__ e2, const float* __restrict__ emb,
        float* __restrict__ q, u16* __restrict__ dq) {
    int wid = threadIdx.x >> 6, lane = threadIdx.x & 63;
    int l15 = lane & 15, lk = lane >> 4;
    int m0 = (blockIdx.x * 4 + wid) * 32;
    short8 zh[2][2], zl[2][2];                 // [half][ks]
    #pragma unroll
    for (int h = 0; h < 2; ++h) {
        int px = m0 + h * 16 + l15;
        const float4* zp = (const float4*)(zf + (size_t)px * 64);
        #pragma unroll
        for (int ks = 0; ks < 2; ++ks) {
            short8 hh, ll;
            #pragma unroll
            for (int j2 = 0; j2 < 2; ++j2) {
                float4 v4 = zp[ks * 8 + lk * 2 + j2];
                float vv[4] = {v4.x, v4.y, v4.z, v4.w};
                #pragma unroll
                for (int j = 0; j < 4; ++j) {
                    u16 hb = f2bf(vv[j]);
                    hh[j2 * 4 + j] = (short)hb;
                    ll[j2 * 4 + j] = (short)f2bf(vv[j] - bf2f(hb));
                }
            }
            zh[h][ks] = hh;
            zl[h][ks] = ll;
        }
    }
    float bs[2] = {3.4e38f, 3.4e38f};
    int   bi[2] = {0, 0};
    for (int tile = 0; tile < 32; ++tile) {
        short8 fh[2], fl[2];
        #pragma unroll
        for (int ks = 0; ks < 2; ++ks) {
            fh[ks] = *(const short8*)(ehi + (size_t)(tile * 16 + l15) * 64 + ks * 32 + lk * 8);
            fl[ks] = *(const short8*)(elo + (size_t)(tile * 16 + l15) * 64 + ks * 32 + lk * 8);
        }
        float4 e2v = *(const float4*)(e2 + tile * 16 + lk * 4);
        float ee[4] = {e2v.x, e2v.y, e2v.z, e2v.w};
        #pragma unroll
        for (int h = 0; h < 2; ++h) {
            f32x4 acc = {};
            #pragma unroll
            for (int ks = 0; ks < 2; ++ks) {
                acc = mfma16(fh[ks], zh[h][ks], acc);
                acc = mfma16(fl[ks], zh[h][ks], acc);
                acc = mfma16(fh[ks], zl[h][ks], acc);
            }
            #pragma unroll
            for (int r = 0; r < 4; ++r) {
                float sc = ee[r] - 2.f * acc[r];
                int ei = tile * 16 + lk * 4 + r;
                if (sc < bs[h]) { bs[h] = sc; bi[h] = ei; }
            }
        }
    }
    #pragma unroll
    for (int h = 0; h < 2; ++h) {
        #pragma unroll
        for (int off = 16; off < 64; off <<= 1) {
            float s2 = __shfl_xor(bs[h], off, 64);
            int   i2 = __shfl_xor(bi[h], off, 64);
            if (s2 < bs[h] || (s2 == bs[h] && i2 < bi[h])) { bs[h] = s2; bi[h] = i2; }
        }
    }
    #pragma unroll
    for (int h = 0; h < 2; ++h) {
        for (int p = 0; p < 16; ++p) {
            int idx = __shfl(bi[h], p, 64);
            int px  = m0 + h * 16 + p;
            float val = emb[(size_t)idx * 64 + lane];
            q[(size_t)px * 64 + lane] = val;
            int xx = px & 63, yy = (px >> 6) & 63, bb = px >> 12;
            dq[((size_t)(bb * 66 + yy + 1) * 66 + xx + 1) * 64 + lane] = f2bf(val);
        }
    }
}

// ---- loss with faithful NCHW pairing: q_flat[i] vs z_nchw(i); z stored NHWC ----
__global__ __launch_bounds__(256) void loss_tr(const float* __restrict__ q,
        const float* __restrict__ z, float* __restrict__ part) {
    __shared__ float zt[64 * 65];
    int bh = blockIdx.x;                       // b*64 + h
    size_t zbase = (size_t)bh * 4096;
    for (int j = threadIdx.x; j < 4096; j += 256) {
        int w = j >> 6, c = j & 63;
        zt[w * 65 + c] = z[zbase + j];
    }
    __syncthreads();
    int b = bh >> 6, h = bh & 63;
    int w = threadIdx.x & 63;
    float s = 0.f;
    #pragma unroll
    for (int k = 0; k < 16; ++k) {
        int cc = (threadIdx.x >> 6) + k * 4;
        float qv = q[(size_t)b * 262144 + (size_t)cc * 4096 + h * 64 + w];
        float d = qv - zt[w * 65 + cc];
        s = fmaf(d, d, s);
    }
    #pragma unroll
    for (int off = 32; off; off >>= 1) s += __shfl_down(s, off, 64);
    __shared__ float red[4];
    int lane = threadIdx.x & 63, wid = threadIdx.x >> 6;
    if (lane == 0) red[wid] = s;
    __syncthreads();
    if (threadIdx.x == 0) part[blockIdx.x] = (red[0] + red[1]) + (red[2] + red[3]);
}

__global__ __launch_bounds__(256) void loss_final(const float* __restrict__ part,
        float* __restrict__ loss, float scale) {
    float s = 0.f;
    for (int i = threadIdx.x; i < 2048; i += 256) s += part[i];
    #pragma unroll
    for (int off = 32; off; off >>= 1) s += __shfl_down(s, off, 64);
    __shared__ float red[4];
    int lane = threadIdx.x & 63, wid = threadIdx.x >> 6;
    if (lane == 0) red[wid] = s;
    __syncthreads();
    if (threadIdx.x == 0)
        *loss = ((red[0] + red[1]) + (red[2] + red[3])) * scale;
}

// ---- deconv1 k4 s2 p1 via MFMA + LDS weights (variant bits above XCD) ----
template<int CO, int NOC, int PT, int HI, int WI, int NYB>
__global__ __launch_bounds__(256) void deconv_lds(const u16* __restrict__ in,
        const u16* __restrict__ wb, const float* __restrict__ bias,
        u16* __restrict__ out) {
    constexpr int HPI = HI + 2, WPI = WI + 2;
    constexpr int HPO = 2 * HI + 2, WPO = 2 * WI + 2;
    constexpr int NF = NOC / 16;
    constexpr int NW16 = 2 * NOC * 256;               // u16 count in LDS
    constexpr int LOG2NYB = (NYB == 4) ? 2 : 1;
    __shared__ u16 wlds[NW16];                        // 32 KB at NOC=32
    int xcd = blockIdx.x & 7;
    int byv = (blockIdx.x >> 3) & (NYB - 1);
    int bx  = (blockIdx.x >> (3 + LOG2NYB)) * 8 + xcd;
    int py = byv & 1;
    int oh = byv >> 1;
    int oc_base = oh * NOC;
    for (int j = threadIdx.x; j < NW16 / 8; j += 256) {
        int u = j * 8;
        int clsl = u / (NOC * 256);
        int rem = u - clsl * (NOC * 256);
        int byteoff = swz<9>(u * 2);
        *(uint4*)((char*)wlds + byteoff) = *(const uint4*)(wb
            + ((size_t)((py * 2 + clsl) * CO + oc_base)) * 256 + rem);
    }
    __syncthreads();
    int sy = py ? 1 : -1;
    int wid = threadIdx.x >> 6, lane = threadIdx.x & 63;
    int m0 = bx * (PT * 64) + wid * (PT * 16);
    int b = m0 / (HI * WI);
    int rem0 = m0 % (HI * WI);
    int y = rem0 / WI, x0 = rem0 % WI;
    int l15 = lane & 15, lk = lane >> 4;

    short8 fbuf[2][3][2][PT];                  // [idy][dx+1][ks][p]
    #pragma unroll
    for (int idy = 0; idy < 2; ++idy) {
        int dy = idy ? sy : 0;
        int rb = (b * HPI + y + dy + 1) * WPI;
        #pragma unroll
        for (int idx = 0; idx < 3; ++idx)
            #pragma unroll
            for (int ks = 0; ks < 2; ++ks)
                #pragma unroll
                for (int p = 0; p < PT; ++p)
                    fbuf[idy][idx][ks][p] = *(const short8*)(in
                        + (size_t)(rb + x0 + p * 16 + l15 + idx) * 64
                        + ks * 32 + lk * 8);
    }

    f32x4 acc[PT][2][NF] = {};
    #pragma unroll
    for (int idy = 0; idy < 2; ++idy)
        #pragma unroll
        for (int idx = 0; idx < 3; ++idx) {
            int dx = idx - 1;
            #pragma unroll
            for (int ks = 0; ks < 2; ++ks)
                #pragma unroll
                for (int pxc = 0; pxc < 2; ++pxc) {
                    int sx = pxc ? 1 : -1;
                    if (!(dx == 0 || dx == sx)) continue;   // compile-time pruned
                    int t = 2 * (idy != 0) + (dx != 0);
                    #pragma unroll
                    for (int f = 0; f < NF; ++f) {
                        int row = pxc * NOC + f * 16 + l15;
                        int byteoff = swz<9>(row * 512 + (t * 2 + ks) * 64 + lk * 16);
                        short8 fa = *(const short8*)((const char*)wlds + byteoff);
                        #pragma unroll
                        for (int p = 0; p < PT; ++p)
                            acc[p][pxc][f] = mfma16(fa, fbuf[idy][idx][ks][p],
                                                    acc[p][pxc][f]);
                    }
                }
        }

    #pragma unroll
    for (int p = 0; p < PT; ++p) {
        int x = x0 + p * 16 + l15;
        #pragma unroll
        for (int pxc = 0; pxc < 2; ++pxc) {
            int oy = 2 * y + py + 1, ox = 2 * x + pxc + 1;
            size_t po = ((size_t)(b * HPO + oy) * WPO + ox) * CO;
            #pragma unroll
            for (int f = 0; f < NF; ++f) {
                int oc0 = oc_base + f * 16 + lk * 4;
                float4 bi = *(const float4*)(bias + oc0);
                float r0 = fmaxf(acc[p][pxc][f][0] + bi.x, 0.f);
                float r1 = fmaxf(acc[p][pxc][f][1] + bi.y, 0.f);
                float r2 = fmaxf(acc[p][pxc][f][2] + bi.z, 0.f);
                float r3 = fmaxf(acc[p][pxc][f][3] + bi.w, 0.f);
                uint2 uu;
                uu.x = (uint)f2bf(r0) | ((uint)f2bf(r1) << 16);
                uu.y = (uint)f2bf(r2) | ((uint)f2bf(r3) << 16);
                *(uint2*)(out + po + oc0) = uu;
            }
        }
    }
}

// ---- deconv2 (64->32, 128x128): R15 structure (input LDS + weight LDS,
// py-split in bit 3), but 512 threads/block: 8 waves x 16 px -> 16 waves/CU. ----
__global__ __launch_bounds__(512) void deconv2_stage(const u16* __restrict__ in,
        const u16* __restrict__ wb, const float* __restrict__ bias,
        u16* __restrict__ out) {
    __shared__ u16 wlds[2 * 32 * 256];         // 32 KB
    __shared__ u16 ilds[2 * 130 * 64];         // 33,280 B
    int xcd = blockIdx.x & 7;
    int py  = (blockIdx.x >> 3) & 1;
    int bx  = (blockIdx.x >> 4) * 8 + xcd;     // 0..4095 = b*128 + y
    int b = bx >> 7;
    int y = bx & 127;
    int sy = py ? 1 : -1;
    // weights: [cls(2) x 32 oc x 256 K], swizzled rows of 512B
    for (int j = threadIdx.x; j < 2048; j += 512) {
        int u = j * 8;
        int clsl = u >> 13;                    // u / 8192
        int rem = u & 8191;
        *(uint4*)((char*)wlds + swz<9>(u * 2)) = *(const uint4*)(wb
            + ((size_t)(py * 2 + clsl) * 32) * 256 + rem);
    }
    // input rows y and y+sy (padded indices +1), full 130-px rows
    int rowg0 = (b * 130 + y + 1) * 130;
    int rowg1 = (b * 130 + y + sy + 1) * 130;
    for (int j = threadIdx.x; j < 2080; j += 512) {
        int row = (j >= 1040);
        int rem = j - row * 1040;
        int px = rem >> 3, c16 = rem & 7;
        int rg = row ? rowg1 : rowg0;
        uint4 v = *(const uint4*)(in + (size_t)(rg + px) * 64 + c16 * 8);
        int lbyte = (j * 16) ^ ((px & 7) << 4);
        *(uint4*)((char*)ilds + lbyte) = v;
    }
    __syncthreads();

    int wid = threadIdx.x >> 6, lane = threadIdx.x & 63;
    int l15 = lane & 15, lk = lane >> 4;
    int xw = wid * 16;                         // wave's first local px (16 each)
    f32x4 acc[2][2] = {};                      // [pxc][f]
    #pragma unroll
    for (int idy = 0; idy < 2; ++idy)
        #pragma unroll
        for (int idx = 0; idx < 3; ++idx) {
            int dx = idx - 1;
            #pragma unroll
            for (int ks = 0; ks < 2; ++ks) {
                int pxl = xw + l15 + idx;      // 0..129
                int lbyte = ((idy * 130 + pxl) * 128 + ks * 64 + lk * 16)
                            ^ ((pxl & 7) << 4);
                short8 fb = *(const short8*)((const char*)ilds + lbyte);
                #pragma unroll
                for (int pxc = 0; pxc < 2; ++pxc) {
                    int sx = pxc ? 1 : -1;
                    if (!(dx == 0 || dx == sx)) continue;
                    int t = 2 * (idy != 0) + (dx != 0);
                    #pragma unroll
                    for (int f = 0; f < 2; ++f) {
                        int row = pxc * 32 + f * 16 + l15;
                        int byteoff = swz<9>(row * 512 + (t * 2 + ks) * 64 + lk * 16);
                        short8 fa = *(const short8*)((const char*)wlds + byteoff);
                        acc[pxc][f] = mfma16(fa, fb, acc[pxc][f]);
                    }
                }
            }
        }

    int x = xw + l15;
    #pragma unroll
    for (int pxc = 0; pxc < 2; ++pxc) {
        int oy = 2 * y + py + 1, ox = 2 * x + pxc + 1;
        size_t po = ((size_t)(b * 258 + oy) * 258 + ox) * 32;
        #pragma unroll
        for (int f = 0; f < 2; ++f) {
            int oc0 = f * 16 + lk * 4;
            float4 bi = *(const float4*)(bias + oc0);
            float r0 = fmaxf(acc[pxc][f][0] + bi.x, 0.f);
            float r1 = fmaxf(acc[pxc][f][1] + bi.y, 0.f);
            float r2 = fmaxf(acc[pxc][f][2] + bi.z, 0.f);
            float r3 = fmaxf(acc[pxc][f][3] + bi.w, 0.f);
            uint2 uu;
            uu.x = (uint)f2bf(r0) | ((uint)f2bf(r1) << 16);
            uu.y = (uint)f2bf(r2) | ((uint)f2bf(r3) << 16);
            *(uint2*)(out + po + oc0) = uu;
        }
    }
}

// ---- conv3 via MFMA: 32->3 k3 s1 p1 + sigmoid; hoisted fb, LDS weights ----
__global__ __launch_bounds__(256) void conv3_mfma(const u16* __restrict__ in,
        const u16* __restrict__ wk, const float* __restrict__ bias,
        float* __restrict__ out) {
    __shared__ u16 walds[16 * 288 * 2];        // 18432 B, swizzled
    for (int j = threadIdx.x; j < 1152; j += 256) {
        int u = j * 8;
        *(uint4*)((char*)walds + swz<9>(u * 2)) = *(const uint4*)(wk + u);
    }
    __syncthreads();
    int wid = threadIdx.x >> 6, lane = threadIdx.x & 63;
    int m0 = (blockIdx.x * 4 + wid) * 16;      // 16 px per wave
    int b   = m0 >> 16;
    int rem = m0 & 65535;
    int y   = rem >> 8;
    int x0  = rem & 255;
    int l15 = lane & 15, lk = lane >> 4;
    short8 fb[3][3];
    #pragma unroll
    for (int dy = 0; dy < 3; ++dy) {
        int rb = (b * 258 + y + dy) * 258;
        #pragma unroll
        for (int dx = 0; dx < 3; ++dx)
            fb[dy][dx] = *(const short8*)(in + (size_t)(rb + x0 + l15 + dx) * 32 + lk * 8);
    }
    f32x4 acc = {};
    #pragma unroll
    for (int ks = 0; ks < 9; ++ks) {
        int base = (l15 * 288 + ks * 32 + lk * 8) * 2;
        short8 fah = *(const short8*)((const char*)walds + swz<9>(base));
        short8 fal = *(const short8*)((const char*)walds + swz<9>(base + 9216));
        acc = mfma16(fah, fb[ks / 3][ks % 3], acc);
        acc = mfma16(fal, fb[ks / 3][ks % 3], acc);
    }
    if (lk == 0) {
        int px = x0 + l15;
        float* ob = out + (size_t)b * 196608 + (size_t)y * 256 + px;
        ob[0]      = 1.f / (1.f + expf(-(acc[0] + bias[0])));
        ob[65536]  = 1.f / (1.f + expf(-(acc[1] + bias[1])));
        ob[131072] = 1.f / (1.f + expf(-(acc[2] + bias[2])));
    }
}

// ---------------- launch ----------------
extern "C" void kernel_launch(void* const* d_in, const int* in_sizes, int n_in,
                              void* d_out, int out_size, void* d_ws, size_t ws_size,
                              hipStream_t stream) {
    (void)in_sizes; (void)n_in; (void)out_size;
    const float* x   = (const float*)d_in[0];
    const float* e1w = (const float*)d_in[1];
    const float* e1b = (const float*)d_in[2];
    const float* e2w = (const float*)d_in[3];
    const float* e2b = (const float*)d_in[4];
    const float* emb = (const float*)d_in[5];
    const float* d1w = (const float*)d_in[6];
    const float* d1b = (const float*)d_in[7];
    const float* d2w = (const float*)d_in[8];
    const float* d2b = (const float*)d_in[9];
    const float* d3w = (const float*)d_in[10];
    const float* d3b = (const float*)d_in[11];

    float* out   = (float*)d_out;
    float* recon = out;                    // 6291456 floats
    float* loss  = out + 6291456;          // 1 float
    float* q     = out + 6291457;          // 8388608 floats (4B-aligned only)

    char* wsb = (char*)d_ws;
    u16*   wt1b = (u16*)(wsb + 0);         // 131072 B
    u16*   wt2b = (u16*)(wsb + 131072);    // 65536 B
    u16*   wc2b = (u16*)(wsb + 196608);    // 65536 B
    float* e2v  = (float*)(wsb + 262144);  // 512 f
    float* prt  = (float*)(wsb + 264192);  // 2048 f -> ends 272384
    u16*   wk3  = (u16*)(wsb + 272384);    // 18432 B -> ends 290816
    u16*   ehib = (u16*)(wsb + 290816);    // 65536 B
    u16*   elob = (u16*)(wsb + 356352);    // 65536 B -> ends 421888
    char*  big  = wsb + 524288;

    u16*   z1p = (u16*)big;                     // 35,145,728 B
    float* zf  = (float*)(big + 35145728);      // 33,554,432 B
    u16* dq = (u16*)big;                        // decoder reuse (z1p dead after conv2)

    size_t avail = ws_size > (size_t)524288 ? ws_size - 524288 : 0;
    int G = 32;
    while (G > 1 && (size_t)17842176 + (size_t)G * 6423296 > avail) G >>= 1;
    int ngrp = BB / G;
    u16* h1p = (u16*)(big + 17842176);
    u16* h2p = (u16*)(big + 17842176 + (size_t)G * 2163200);

    // weight prep
    wt_deconv<64, 64><<<256, 256, 0, stream>>>(d1w, wt1b);
    wt_deconv<64, 32><<<128, 256, 0, stream>>>(d2w, wt2b);
    wt_conv2<<<128, 256, 0, stream>>>(e2w, wc2b);
    wt_conv3<<<18, 256, 0, stream>>>(d3w, wk3);
    wt_emb<<<128, 256, 0, stream>>>(emb, ehib, elob);
    e2_kernel<<<8, 64, 0, stream>>>(emb, e2v);

    // encoder (full batch)
    border_zero<32, 131, 131, 128, 128><<<2146, 256, 0, stream>>>(z1p, 32);
    conv1_kernel<<<2048, 256, 0, stream>>>(x, e1w, e1b, z1p);
    conv2_mfma<<<2048, 256, 0, stream>>>(z1p, wc2b, e2b, zf);
    // z1p dead now; dq aliases it — zero its border, then vq writes q AND dq
    border_zero<64, 66, 66, 64, 64><<<545, 256, 0, stream>>>(dq, 32);
    vq_mfma<<<1024, 256, 0, stream>>>(zf, ehib, elob, e2v, emb, q, dq);
    loss_tr<<<2048, 256, 0, stream>>>(q, zf, prt);

    // decoder
    border_zero<64, 130, 130, 128, 128><<<(G * 16900 + 255) / 256, 256, 0, stream>>>(h1p, G);
    border_zero<32, 258, 258, 256, 256><<<(G * 66564 + 255) / 256, 256, 0, stream>>>(h2p, G);
    for (int g = 0; g < ngrp; ++g) {
        u16* dqg = dq + (size_t)g * G * 278784;
        // deconv1: 64->64, NOC=32, PT=2, 4 class-variants in bits 3-4
        deconv_lds<64, 32, 2, 64, 64, 4>
            <<<G * 32 * 4, 256, 0, stream>>>(dqg, wt1b, d1b, h1p);
        // deconv2: R15 structure, 512-thread blocks (16 waves/CU)
        deconv2_stage<<<G * 128 * 2, 512, 0, stream>>>(h1p, wt2b, d2b, h2p);
        conv3_mfma<<<G * 1024, 256, 0, stream>>>(h2p, wk3, d3b,
                                                 recon + (size_t)g * G * 196608);
    }
    loss_final<<<1, 256, 0, stream>>>(prt, loss, 1.25f / (float)NZ);
}

// Round 18
// 433.386 us; speedup vs baseline: 1.2648x; 1.0397x over previous
//
#include <hip/hip_runtime.h>
#include <math.h>

// ---------------- problem constants ----------------
#define BB    32
#define C_IN  3
#define H0    256
#define W0    256
#define C1    32
#define H1    128
#define W1    128
#define C2    64
#define H2    64
#define W2    64
#define HW2   (H2*W2)     // 4096
#define N_EMB 512
#define E_DIM 64
#define NZ    (BB*C2*HW2) // 8388608
#define NPX   (BB*HW2)    // 131072 pixels in VQ

typedef unsigned short u16;
typedef unsigned int   uint;
typedef __attribute__((ext_vector_type(8))) short short8;
typedef __attribute__((ext_vector_type(4))) float f32x4;

__device__ inline u16 f2bf(float f) {
    uint u = __builtin_bit_cast(uint, f);
    u += 0x7FFF + ((u >> 16) & 1);          // RNE
    return (u16)(u >> 16);
}
__device__ inline float bf2f(u16 h) {
    uint u = (uint)h << 16;
    return __builtin_bit_cast(float, u);
}
__device__ inline f32x4 mfma16(short8 a, short8 b, f32x4 c) {
    return __builtin_amdgcn_mfma_f32_16x16x32_bf16(a, b, c, 0, 0, 0);
}
// XOR-swizzle for LDS row-major weight tiles (rows = 1<<RS bytes)
template<int RS>
__device__ inline int swz(int off) { return off ^ (((off >> RS) & 7) << 4); }

// ---- zero the halo border of an NHWC padded buffer (interior at (1,1)) ----
template<int C, int HP, int WP, int H, int W>
__global__ __launch_bounds__(256) void border_zero(u16* buf, int nimg) {
    int t = blockIdx.x * 256 + threadIdx.x;
    if (t >= nimg * HP * WP) return;
    int x = t % WP, y = (t / WP) % HP;
    if (y >= 1 && y < 1 + H && x >= 1 && x < 1 + W) return;
    uint4 z4; z4.x = 0; z4.y = 0; z4.z = 0; z4.w = 0;
    uint4* p = (uint4*)(buf + (size_t)t * C);
    #pragma unroll
    for (int i = 0; i < C / 8; ++i) p[i] = z4;
}

// ---- weight prep: deconv (CI,CO,4,4) fp32 -> bf16 [cls][oc][t*CI+ic] ----
template<int CI, int CO>
__global__ __launch_bounds__(256) void wt_deconv(const float* __restrict__ w,
        u16* __restrict__ wb) {
    int i = blockIdx.x * 256 + threadIdx.x;
    if (i >= 4 * CO * 4 * CI) return;
    int ic  = i % CI;
    int t   = (i / CI) & 3;
    int oc  = (i / (CI * 4)) % CO;
    int cls = i / (CI * 4 * CO);
    int py = cls >> 1, px = cls & 1, ty = t >> 1, tx = t & 1;
    int ky = py ? (ty ? 0 : 2) : (ty ? 3 : 1);
    int kx = px ? (tx ? 0 : 2) : (tx ? 3 : 1);
    wb[i] = f2bf(w[(((size_t)ic * CO + oc) * 4 + ky) * 4 + kx]);
}

// ---- weight prep: conv2 (64,32,4,4) fp32 -> bf16 [oc][tap*32+ic] ----
__global__ __launch_bounds__(256) void wt_conv2(const float* __restrict__ w,
        u16* __restrict__ wb) {
    int i = blockIdx.x * 256 + threadIdx.x;
    if (i >= 64 * 512) return;
    int ic = i & 31;
    int k  = (i >> 5) & 15;
    int oc = i >> 9;
    wb[i] = f2bf(w[(size_t)(oc * 32 + ic) * 16 + k]);
}

// ---- weight prep: conv3 (3,32,3,3) fp32 -> split-bf16 [hi/lo][oc16][tap*32+ic]
__global__ __launch_bounds__(256) void wt_conv3(const float* __restrict__ w,
        u16* __restrict__ wk) {
    int i = blockIdx.x * 256 + threadIdx.x;
    if (i >= 16 * 288) return;
    int ic = i & 31;
    int k  = (i / 32) % 9;
    int oc = i / 288;
    float hi = 0.f, lo = 0.f;
    if (oc < 3) {
        float v = w[(size_t)(oc * 32 + ic) * 9 + k];
        hi = bf2f(f2bf(v));
        lo = v - hi;
    }
    wk[i]            = f2bf(hi);
    wk[i + 16 * 288] = f2bf(lo);
}

// ---- emb prep: fp32 (512,64) -> split-bf16 tables ehi/elo [e][c] ----
__global__ __launch_bounds__(256) void wt_emb(const float* __restrict__ emb,
        u16* __restrict__ ehi, u16* __restrict__ elo) {
    int i = blockIdx.x * 256 + threadIdx.x;      // 32768
    float v = emb[i];
    u16 h = f2bf(v);
    ehi[i] = h;
    elo[i] = f2bf(v - bf2f(h));
}

// ---- conv1: 3->32, k4 s2 p1, ReLU; out = NHWC bf16 padded (131x131) ----
__global__ __launch_bounds__(256) void conv1_kernel(const float* __restrict__ x,
        const float* __restrict__ w, const float* __restrict__ bias,
        u16* __restrict__ out) {
    int t = blockIdx.x * 256 + threadIdx.x;           // 32*128*128
    int ox = t & (W1 - 1);
    int oy = (t >> 7) & (H1 - 1);
    int b  = t >> 14;
    const float* xb = x + (size_t)b * (C_IN * H0 * W0);
    float v[48];
    #pragma unroll
    for (int ic = 0; ic < 3; ++ic)
        #pragma unroll
        for (int dy = 0; dy < 4; ++dy) {
            int iy = oy * 2 - 1 + dy;
            #pragma unroll
            for (int dx = 0; dx < 4; ++dx) {
                int ix = ox * 2 - 1 + dx;
                float val = 0.f;
                if ((unsigned)iy < H0 && (unsigned)ix < W0)
                    val = xb[((size_t)ic * H0 + iy) * W0 + ix];
                v[(ic * 4 + dy) * 4 + dx] = val;
            }
        }
    u16 h[32];
    #pragma unroll
    for (int oc = 0; oc < C1; ++oc) {
        float a = bias[oc];
        #pragma unroll
        for (int k = 0; k < 48; ++k) a = fmaf(v[k], w[oc * 48 + k], a);
        h[oc] = f2bf(fmaxf(a, 0.f));
    }
    uint4* dst = (uint4*)(out + ((size_t)(b * 131 + oy + 1) * 131 + ox + 1) * 32);
    #pragma unroll
    for (int i = 0; i < 4; ++i) {
        uint4 u;
        u.x = (uint)h[i*8+0] | ((uint)h[i*8+1] << 16);
        u.y = (uint)h[i*8+2] | ((uint)h[i*8+3] << 16);
        u.z = (uint)h[i*8+4] | ((uint)h[i*8+5] << 16);
        u.w = (uint)h[i*8+6] | ((uint)h[i*8+7] << 16);
        dst[i] = u;
    }
}

// ---- conv2 via MFMA + LDS weights: 32->64 k4 s2; oc-half in bit 3 (XCD) ----
__global__ __launch_bounds__(256) void conv2_mfma(const u16* __restrict__ z1p,
        const u16* __restrict__ wb, const float* __restrict__ bias,
        float* __restrict__ z) {
    __shared__ u16 wlds[32 * 512];                    // 32 KB: 32 oc x 512 K
    int xcd = blockIdx.x & 7;
    int oh  = (blockIdx.x >> 3) & 1;
    int bx  = (blockIdx.x >> 4) * 8 + xcd;
    for (int j = threadIdx.x; j < 2048; j += 256) {   // 2048 x 16B
        int u = j * 8;
        int byteoff = swz<10>(u * 2);
        *(uint4*)((char*)wlds + byteoff) =
            *(const uint4*)(wb + (size_t)(oh * 32) * 512 + u);
    }
    __syncthreads();
    int wid = threadIdx.x >> 6, lane = threadIdx.x & 63;
    int m0 = bx * 128 + wid * 32;                     // 32 pixels per wave
    int b  = m0 >> 12;
    int y  = (m0 >> 6) & 63;
    int x0 = m0 & 63;
    int l15 = lane & 15, lk = lane >> 4;
    f32x4 acc[2][2] = {};
    int xA = x0 + l15, xB = x0 + 16 + l15;
    for (int ks = 0; ks < 16; ++ks) {
        int dy = ks >> 2, dx = ks & 3;
        int rb = (b * 131 + 2 * y + dy) * 131;
        short8 fbA = *(const short8*)(z1p + ((size_t)(rb + 2 * xA + dx)) * 32 + lk * 8);
        short8 fbB = *(const short8*)(z1p + ((size_t)(rb + 2 * xB + dx)) * 32 + lk * 8);
        #pragma unroll
        for (int f = 0; f < 2; ++f) {
            int byteoff = swz<10>((f * 16 + l15) * 1024 + ks * 64 + lk * 16);
            short8 fa = *(const short8*)((const char*)wlds + byteoff);
            acc[0][f] = mfma16(fa, fbA, acc[0][f]);
            acc[1][f] = mfma16(fa, fbB, acc[1][f]);
        }
    }
    #pragma unroll
    for (int p = 0; p < 2; ++p) {
        int pix = m0 + p * 16 + l15;
        #pragma unroll
        for (int f = 0; f < 2; ++f) {
            int oc0 = oh * 32 + f * 16 + lk * 4;
            float4 bi = *(const float4*)(bias + oc0);
            float4 r;
            r.x = fmaxf(acc[p][f][0] + bi.x, 0.f);
            r.y = fmaxf(acc[p][f][1] + bi.y, 0.f);
            r.z = fmaxf(acc[p][f][2] + bi.z, 0.f);
            r.w = fmaxf(acc[p][f][3] + bi.w, 0.f);
            *(float4*)(z + (size_t)pix * 64 + oc0) = r;
        }
    }
}

// ---------------- embedding squared norms ----------------
__global__ void e2_kernel(const float* __restrict__ emb, float* __restrict__ e2) {
    int e = blockIdx.x * 64 + threadIdx.x;
    float s = 0.f;
    #pragma unroll
    for (int c = 0; c < E_DIM; ++c) {
        float v = emb[(size_t)e * E_DIM + c];
        s = fmaf(v, v, s);
    }
    e2[e] = s;
}

// ---- VQ via MFMA (split-bf16); gather writes BOTH q (fp32 flat) and
// dq (bf16 NHWC padded 66x66) — q_transpose fused away. ----
__global__ __launch_bounds__(256) void vq_mfma(const float* __restrict__ zf,
        const u16* __restrict__ ehi, const u16* __restrict__ elo,
        const float* __restrict__ e2, const float* __restrict__ emb,
        float* __restrict__ q, u16* __restrict__ dq) {
    int wid = threadIdx.x >> 6, lane = threadIdx.x & 63;
    int l15 = lane & 15, lk = lane >> 4;
    int m0 = (blockIdx.x * 4 + wid) * 32;
    short8 zh[2][2], zl[2][2];                 // [half][ks]
    #pragma unroll
    for (int h = 0; h < 2; ++h) {
        int px = m0 + h * 16 + l15;
        const float4* zp = (const float4*)(zf + (size_t)px * 64);
        #pragma unroll
        for (int ks = 0; ks < 2; ++ks) {
            short8 hh, ll;
            #pragma unroll
            for (int j2 = 0; j2 < 2; ++j2) {
                float4 v4 = zp[ks * 8 + lk * 2 + j2];
                float vv[4] = {v4.x, v4.y, v4.z, v4.w};
                #pragma unroll
                for (int j = 0; j < 4; ++j) {
                    u16 hb = f2bf(vv[j]);
                    hh[j2 * 4 + j] = (short)hb;
                    ll[j2 * 4 + j] = (short)f2bf(vv[j] - bf2f(hb));
                }
            }
            zh[h][ks] = hh;
            zl[h][ks] = ll;
        }
    }
    float bs[2] = {3.4e38f, 3.4e38f};
    int   bi[2] = {0, 0};
    for (int tile = 0; tile < 32; ++tile) {
        short8 fh[2], fl[2];
        #pragma unroll
        for (int ks = 0; ks < 2; ++ks) {
            fh[ks] = *(const short8*)(ehi + (size_t)(tile * 16 + l15) * 64 + ks * 32 + lk * 8);
            fl[ks] = *(const short8*)(elo + (size_t)(tile * 16 + l15) * 64 + ks * 32 + lk * 8);
        }
        float4 e2v = *(const float4*)(e2 + tile * 16 + lk * 4);
        float ee[4] = {e2v.x, e2v.y, e2v.z, e2v.w};
        #pragma unroll
        for (int h = 0; h < 2; ++h) {
            f32x4 acc = {};
            #pragma unroll
            for (int ks = 0; ks < 2; ++ks) {
                acc = mfma16(fh[ks], zh[h][ks], acc);
                acc = mfma16(fl[ks], zh[h][ks], acc);
                acc = mfma16(fh[ks], zl[h][ks], acc);
            }
            #pragma unroll
            for (int r = 0; r < 4; ++r) {
                float sc = ee[r] - 2.f * acc[r];
                int ei = tile * 16 + lk * 4 + r;
                if (sc < bs[h]) { bs[h] = sc; bi[h] = ei; }
            }
        }
    }
    #pragma unroll
    for (int h = 0; h < 2; ++h) {
        #pragma unroll
        for (int off = 16; off < 64; off <<= 1) {
            float s2 = __shfl_xor(bs[h], off, 64);
            int   i2 = __shfl_xor(bi[h], off, 64);
            if (s2 < bs[h] || (s2 == bs[h] && i2 < bi[h])) { bs[h] = s2; bi[h] = i2; }
        }
    }
    #pragma unroll
    for (int h = 0; h < 2; ++h) {
        for (int p = 0; p < 16; ++p) {
            int idx = __shfl(bi[h], p, 64);
            int px  = m0 + h * 16 + p;
            float val = emb[(size_t)idx * 64 + lane];
            q[(size_t)px * 64 + lane] = val;
            int xx = px & 63, yy = (px >> 6) & 63, bb = px >> 12;
            dq[((size_t)(bb * 66 + yy + 1) * 66 + xx + 1) * 64 + lane] = f2bf(val);
        }
    }
}

// ---- loss with faithful NCHW pairing: q_flat[i] vs z_nchw(i); z stored NHWC ----
__global__ __launch_bounds__(256) void loss_tr(const float* __restrict__ q,
        const float* __restrict__ z, float* __restrict__ part) {
    __shared__ float zt[64 * 65];
    int bh = blockIdx.x;                       // b*64 + h
    size_t zbase = (size_t)bh * 4096;
    for (int j = threadIdx.x; j < 4096; j += 256) {
        int w = j >> 6, c = j & 63;
        zt[w * 65 + c] = z[zbase + j];
    }
    __syncthreads();
    int b = bh >> 6, h = bh & 63;
    int w = threadIdx.x & 63;
    float s = 0.f;
    #pragma unroll
    for (int k = 0; k < 16; ++k) {
        int cc = (threadIdx.x >> 6) + k * 4;
        float qv = q[(size_t)b * 262144 + (size_t)cc * 4096 + h * 64 + w];
        float d = qv - zt[w * 65 + cc];
        s = fmaf(d, d, s);
    }
    #pragma unroll
    for (int off = 32; off; off >>= 1) s += __shfl_down(s, off, 64);
    __shared__ float red[4];
    int lane = threadIdx.x & 63, wid = threadIdx.x >> 6;
    if (lane == 0) red[wid] = s;
    __syncthreads();
    if (threadIdx.x == 0) part[blockIdx.x] = (red[0] + red[1]) + (red[2] + red[3]);
}

__global__ __launch_bounds__(256) void loss_final(const float* __restrict__ part,
        float* __restrict__ loss, float scale) {
    float s = 0.f;
    for (int i = threadIdx.x; i < 2048; i += 256) s += part[i];
    #pragma unroll
    for (int off = 32; off; off >>= 1) s += __shfl_down(s, off, 64);
    __shared__ float red[4];
    int lane = threadIdx.x & 63, wid = threadIdx.x >> 6;
    if (lane == 0) red[wid] = s;
    __syncthreads();
    if (threadIdx.x == 0)
        *loss = ((red[0] + red[1]) + (red[2] + red[3])) * scale;
}

// ---- deconv1 (64->64, 64x64) LDS-staged: block = (b, row-pair, py, oh) ----
// Stages 3 input rows (3x66x64 = 25KB, XOR-swizzled) + 32KB weights (2 px-
// classes x 32 oc). 512 thr: 8 waves x 16 px over 2 output rows; all MFMA
// operands from LDS. py/oh in bits 3-4 (XCD-aligned) -> L2-shared dq reads.
__global__ __launch_bounds__(512) void deconv1_stage(const u16* __restrict__ in,
        const u16* __restrict__ wb, const float* __restrict__ bias,
        u16* __restrict__ out) {
    __shared__ u16 wlds[2 * 32 * 256];         // 32 KB
    __shared__ u16 ilds[3 * 66 * 64];          // 25,344 B
    int xcd = blockIdx.x & 7;
    int pv  = (blockIdx.x >> 3) & 3;
    int bx  = (blockIdx.x >> 5) * 8 + xcd;     // 0..1023 = b*32 + ry
    int py = pv & 1;
    int oh = pv >> 1;
    int b  = bx >> 5;
    int y0 = (bx & 31) * 2;                    // output row pair y0, y0+1
    // weights: cls pair (py*2+0, py*2+1), oc-half oh
    for (int j = threadIdx.x; j < 2048; j += 512) {
        int u = j * 8;
        int clsl = u >> 13;
        int rem = u & 8191;
        *(uint4*)((char*)wlds + swz<9>(u * 2)) = *(const uint4*)(wb
            + ((size_t)((py * 2 + clsl) * 64 + oh * 32)) * 256 + rem);
    }
    // input rows rows_start..rows_start+2 (padded +1)
    int rows_start = y0 - 1 + py;
    for (int j = threadIdx.x; j < 1584; j += 512) {
        int rr = j / 528;
        int rem = j - rr * 528;
        int px = rem >> 3, c16 = rem & 7;
        uint4 v = *(const uint4*)(in
            + ((size_t)(b * 66 + rows_start + 1 + rr) * 66 + px) * 64 + c16 * 8);
        int lbyte = (j * 16) ^ ((px & 7) << 4);
        *(uint4*)((char*)ilds + lbyte) = v;
    }
    __syncthreads();

    int wid = threadIdx.x >> 6, lane = threadIdx.x & 63;
    int l15 = lane & 15, lk = lane >> 4;
    int pxb = wid * 16;                        // local px 0..127 over 2 rows
    int r   = pxb >> 6;                        // 0 or 1 (output row within pair)
    int xw  = pxb & 63;
    int y   = y0 + r;
    f32x4 acc[2][2] = {};                      // [pxc][f]
    #pragma unroll
    for (int idy = 0; idy < 2; ++idy) {
        int rr = r + (idy ? py : (1 - py));    // stage row index for this tap
        #pragma unroll
        for (int idx = 0; idx < 3; ++idx) {
            int dx = idx - 1;
            #pragma unroll
            for (int ks = 0; ks < 2; ++ks) {
                int pxl = xw + l15 + idx;      // padded col 0..65
                int lbyte = ((rr * 66 + pxl) * 128 + ks * 64 + lk * 16)
                            ^ ((pxl & 7) << 4);
                short8 fb = *(const short8*)((const char*)ilds + lbyte);
                #pragma unroll
                for (int pxc = 0; pxc < 2; ++pxc) {
                    int sx = pxc ? 1 : -1;
                    if (!(dx == 0 || dx == sx)) continue;
                    int t = 2 * (idy != 0) + (dx != 0);
                    #pragma unroll
                    for (int f = 0; f < 2; ++f) {
                        int row = pxc * 32 + f * 16 + l15;
                        int byteoff = swz<9>(row * 512 + (t * 2 + ks) * 64 + lk * 16);
                        short8 fa = *(const short8*)((const char*)wlds + byteoff);
                        acc[pxc][f] = mfma16(fa, fb, acc[pxc][f]);
                    }
                }
            }
        }
    }

    int x = xw + l15;
    #pragma unroll
    for (int pxc = 0; pxc < 2; ++pxc) {
        int oy = 2 * y + py + 1, ox = 2 * x + pxc + 1;
        size_t po = ((size_t)(b * 130 + oy) * 130 + ox) * 64;
        #pragma unroll
        for (int f = 0; f < 2; ++f) {
            int oc0 = oh * 32 + f * 16 + lk * 4;
            float4 bi = *(const float4*)(bias + oc0);
            float r0 = fmaxf(acc[pxc][f][0] + bi.x, 0.f);
            float r1 = fmaxf(acc[pxc][f][1] + bi.y, 0.f);
            float r2 = fmaxf(acc[pxc][f][2] + bi.z, 0.f);
            float r3 = fmaxf(acc[pxc][f][3] + bi.w, 0.f);
            uint2 uu;
            uu.x = (uint)f2bf(r0) | ((uint)f2bf(r1) << 16);
            uu.y = (uint)f2bf(r2) | ((uint)f2bf(r3) << 16);
            *(uint2*)(out + po + oc0) = uu;
        }
    }
}

// ---- deconv2 (64->32, 128x128): input LDS + weight LDS, 512 threads ----
__global__ __launch_bounds__(512) void deconv2_stage(const u16* __restrict__ in,
        const u16* __restrict__ wb, const float* __restrict__ bias,
        u16* __restrict__ out) {
    __shared__ u16 wlds[2 * 32 * 256];         // 32 KB
    __shared__ u16 ilds[2 * 130 * 64];         // 33,280 B
    int xcd = blockIdx.x & 7;
    int py  = (blockIdx.x >> 3) & 1;
    int bx  = (blockIdx.x >> 4) * 8 + xcd;     // 0..4095 = b*128 + y
    int b = bx >> 7;
    int y = bx & 127;
    int sy = py ? 1 : -1;
    for (int j = threadIdx.x; j < 2048; j += 512) {
        int u = j * 8;
        int clsl = u >> 13;
        int rem = u & 8191;
        *(uint4*)((char*)wlds + swz<9>(u * 2)) = *(const uint4*)(wb
            + ((size_t)(py * 2 + clsl) * 32) * 256 + rem);
    }
    int rowg0 = (b * 130 + y + 1) * 130;
    int rowg1 = (b * 130 + y + sy + 1) * 130;
    for (int j = threadIdx.x; j < 2080; j += 512) {
        int row = (j >= 1040);
        int rem = j - row * 1040;
        int px = rem >> 3, c16 = rem & 7;
        int rg = row ? rowg1 : rowg0;
        uint4 v = *(const uint4*)(in + (size_t)(rg + px) * 64 + c16 * 8);
        int lbyte = (j * 16) ^ ((px & 7) << 4);
        *(uint4*)((char*)ilds + lbyte) = v;
    }
    __syncthreads();

    int wid = threadIdx.x >> 6, lane = threadIdx.x & 63;
    int l15 = lane & 15, lk = lane >> 4;
    int xw = wid * 16;
    f32x4 acc[2][2] = {};                      // [pxc][f]
    #pragma unroll
    for (int idy = 0; idy < 2; ++idy)
        #pragma unroll
        for (int idx = 0; idx < 3; ++idx) {
            int dx = idx - 1;
            #pragma unroll
            for (int ks = 0; ks < 2; ++ks) {
                int pxl = xw + l15 + idx;
                int lbyte = ((idy * 130 + pxl) * 128 + ks * 64 + lk * 16)
                            ^ ((pxl & 7) << 4);
                short8 fb = *(const short8*)((const char*)ilds + lbyte);
                #pragma unroll
                for (int pxc = 0; pxc < 2; ++pxc) {
                    int sx = pxc ? 1 : -1;
                    if (!(dx == 0 || dx == sx)) continue;
                    int t = 2 * (idy != 0) + (dx != 0);
                    #pragma unroll
                    for (int f = 0; f < 2; ++f) {
                        int row = pxc * 32 + f * 16 + l15;
                        int byteoff = swz<9>(row * 512 + (t * 2 + ks) * 64 + lk * 16);
                        short8 fa = *(const short8*)((const char*)wlds + byteoff);
                        acc[pxc][f] = mfma16(fa, fb, acc[pxc][f]);
                    }
                }
            }
        }

    int x = xw + l15;
    #pragma unroll
    for (int pxc = 0; pxc < 2; ++pxc) {
        int oy = 2 * y + py + 1, ox = 2 * x + pxc + 1;
        size_t po = ((size_t)(b * 258 + oy) * 258 + ox) * 32;
        #pragma unroll
        for (int f = 0; f < 2; ++f) {
            int oc0 = f * 16 + lk * 4;
            float4 bi = *(const float4*)(bias + oc0);
            float r0 = fmaxf(acc[pxc][f][0] + bi.x, 0.f);
            float r1 = fmaxf(acc[pxc][f][1] + bi.y, 0.f);
            float r2 = fmaxf(acc[pxc][f][2] + bi.z, 0.f);
            float r3 = fmaxf(acc[pxc][f][3] + bi.w, 0.f);
            uint2 uu;
            uu.x = (uint)f2bf(r0) | ((uint)f2bf(r1) << 16);
            uu.y = (uint)f2bf(r2) | ((uint)f2bf(r3) << 16);
            *(uint2*)(out + po + oc0) = uu;
        }
    }
}

// ---- conv3 via MFMA: 32->3 k3 s1 p1 + sigmoid; hoisted fb, LDS weights ----
__global__ __launch_bounds__(256) void conv3_mfma(const u16* __restrict__ in,
        const u16* __restrict__ wk, const float* __restrict__ bias,
        float* __restrict__ out) {
    __shared__ u16 walds[16 * 288 * 2];        // 18432 B, swizzled
    for (int j = threadIdx.x; j < 1152; j += 256) {
        int u = j * 8;
        *(uint4*)((char*)walds + swz<9>(u * 2)) = *(const uint4*)(wk + u);
    }
    __syncthreads();
    int wid = threadIdx.x >> 6, lane = threadIdx.x & 63;
    int m0 = (blockIdx.x * 4 + wid) * 16;      // 16 px per wave
    int b   = m0 >> 16;
    int rem = m0 & 65535;
    int y   = rem >> 8;
    int x0  = rem & 255;
    int l15 = lane & 15, lk = lane >> 4;
    short8 fb[3][3];
    #pragma unroll
    for (int dy = 0; dy < 3; ++dy) {
        int rb = (b * 258 + y + dy) * 258;
        #pragma unroll
        for (int dx = 0; dx < 3; ++dx)
            fb[dy][dx] = *(const short8*)(in + (size_t)(rb + x0 + l15 + dx) * 32 + lk * 8);
    }
    f32x4 acc = {};
    #pragma unroll
    for (int ks = 0; ks < 9; ++ks) {
        int base = (l15 * 288 + ks * 32 + lk * 8) * 2;
        short8 fah = *(const short8*)((const char*)walds + swz<9>(base));
        short8 fal = *(const short8*)((const char*)walds + swz<9>(base + 9216));
        acc = mfma16(fah, fb[ks / 3][ks % 3], acc);
        acc = mfma16(fal, fb[ks / 3][ks % 3], acc);
    }
    if (lk == 0) {
        int px = x0 + l15;
        float* ob = out + (size_t)b * 196608 + (size_t)y * 256 + px;
        ob[0]      = 1.f / (1.f + expf(-(acc[0] + bias[0])));
        ob[65536]  = 1.f / (1.f + expf(-(acc[1] + bias[1])));
        ob[131072] = 1.f / (1.f + expf(-(acc[2] + bias[2])));
    }
}

// ---------------- launch ----------------
extern "C" void kernel_launch(void* const* d_in, const int* in_sizes, int n_in,
                              void* d_out, int out_size, void* d_ws, size_t ws_size,
                              hipStream_t stream) {
    (void)in_sizes; (void)n_in; (void)out_size;
    const float* x   = (const float*)d_in[0];
    const float* e1w = (const float*)d_in[1];
    const float* e1b = (const float*)d_in[2];
    const float* e2w = (const float*)d_in[3];
    const float* e2b = (const float*)d_in[4];
    const float* emb = (const float*)d_in[5];
    const float* d1w = (const float*)d_in[6];
    const float* d1b = (const float*)d_in[7];
    const float* d2w = (const float*)d_in[8];
    const float* d2b = (const float*)d_in[9];
    const float* d3w = (const float*)d_in[10];
    const float* d3b = (const float*)d_in[11];

    float* out   = (float*)d_out;
    float* recon = out;                    // 6291456 floats
    float* loss  = out + 6291456;          // 1 float
    float* q     = out + 6291457;          // 8388608 floats (4B-aligned only)

    char* wsb = (char*)d_ws;
    u16*   wt1b = (u16*)(wsb + 0);         // 131072 B
    u16*   wt2b = (u16*)(wsb + 131072);    // 65536 B
    u16*   wc2b = (u16*)(wsb + 196608);    // 65536 B
    float* e2v  = (float*)(wsb + 262144);  // 512 f
    float* prt  = (float*)(wsb + 264192);  // 2048 f -> ends 272384
    u16*   wk3  = (u16*)(wsb + 272384);    // 18432 B -> ends 290816
    u16*   ehib = (u16*)(wsb + 290816);    // 65536 B
    u16*   elob = (u16*)(wsb + 356352);    // 65536 B -> ends 421888
    char*  big  = wsb + 524288;

    u16*   z1p = (u16*)big;                     // 35,145,728 B
    float* zf  = (float*)(big + 35145728);      // 33,554,432 B
    u16* dq = (u16*)big;                        // decoder reuse (z1p dead after conv2)

    size_t avail = ws_size > (size_t)524288 ? ws_size - 524288 : 0;
    int G = 32;
    while (G > 1 && (size_t)17842176 + (size_t)G * 6423296 > avail) G >>= 1;
    int ngrp = BB / G;
    u16* h1p = (u16*)(big + 17842176);
    u16* h2p = (u16*)(big + 17842176 + (size_t)G * 2163200);

    // weight prep
    wt_deconv<64, 64><<<256, 256, 0, stream>>>(d1w, wt1b);
    wt_deconv<64, 32><<<128, 256, 0, stream>>>(d2w, wt2b);
    wt_conv2<<<128, 256, 0, stream>>>(e2w, wc2b);
    wt_conv3<<<18, 256, 0, stream>>>(d3w, wk3);
    wt_emb<<<128, 256, 0, stream>>>(emb, ehib, elob);
    e2_kernel<<<8, 64, 0, stream>>>(emb, e2v);

    // encoder (full batch)
    border_zero<32, 131, 131, 128, 128><<<2146, 256, 0, stream>>>(z1p, 32);
    conv1_kernel<<<2048, 256, 0, stream>>>(x, e1w, e1b, z1p);
    conv2_mfma<<<2048, 256, 0, stream>>>(z1p, wc2b, e2b, zf);
    // z1p dead now; dq aliases it — zero its border, then vq writes q AND dq
    border_zero<64, 66, 66, 64, 64><<<545, 256, 0, stream>>>(dq, 32);
    vq_mfma<<<1024, 256, 0, stream>>>(zf, ehib, elob, e2v, emb, q, dq);
    loss_tr<<<2048, 256, 0, stream>>>(q, zf, prt);

    // decoder
    border_zero<64, 130, 130, 128, 128><<<(G * 16900 + 255) / 256, 256, 0, stream>>>(h1p, G);
    border_zero<32, 258, 258, 256, 256><<<(G * 66564 + 255) / 256, 256, 0, stream>>>(h2p, G);
    for (int g = 0; g < ngrp; ++g) {
        u16* dqg = dq + (size_t)g * G * 278784;
        // deconv1: LDS-staged, (py,oh) in bits 3-4, 512 threads
        deconv1_stage<<<G * 32 * 4, 512, 0, stream>>>(dqg, wt1b, d1b, h1p);
        // deconv2: LDS-staged, py in bit 3, 512 threads
        deconv2_stage<<<G * 128 * 2, 512, 0, stream>>>(h1p, wt2b, d2b, h2p);
        conv3_mfma<<<G * 1024, 256, 0, stream>>>(h2p, wk3, d3b,
                                                 recon + (size_t)g * G * 196608);
    }
    loss_final<<<1, 256, 0, stream>>>(prt, loss, 1.25f / (float)NZ);
}

// Round 19
// 414.910 us; speedup vs baseline: 1.3211x; 1.0445x over previous
//
#include <hip/hip_runtime.h>
#include <math.h>

// ---------------- problem constants ----------------
#define BB    32
#define C_IN  3
#define H0    256
#define W0    256
#define C1    32
#define H1    128
#define W1    128
#define C2    64
#define H2    64
#define W2    64
#define HW2   (H2*W2)     // 4096
#define N_EMB 512
#define E_DIM 64
#define NZ    (BB*C2*HW2) // 8388608
#define NPX   (BB*HW2)    // 131072 pixels in VQ

typedef unsigned short u16;
typedef unsigned int   uint;
typedef __attribute__((ext_vector_type(8))) short short8;
typedef __attribute__((ext_vector_type(4))) float f32x4;

__device__ inline u16 f2bf(float f) {
    uint u = __builtin_bit_cast(uint, f);
    u += 0x7FFF + ((u >> 16) & 1);          // RNE
    return (u16)(u >> 16);
}
__device__ inline float bf2f(u16 h) {
    uint u = (uint)h << 16;
    return __builtin_bit_cast(float, u);
}
__device__ inline f32x4 mfma16(short8 a, short8 b, f32x4 c) {
    return __builtin_amdgcn_mfma_f32_16x16x32_bf16(a, b, c, 0, 0, 0);
}
// XOR-swizzle for LDS row-major weight tiles (rows = 1<<RS bytes)
template<int RS>
__device__ inline int swz(int off) { return off ^ (((off >> RS) & 7) << 4); }

// ---- zero the halo border of an NHWC padded buffer (interior at (1,1)) ----
template<int C, int HP, int WP, int H, int W>
__global__ __launch_bounds__(256) void border_zero(u16* buf, int nimg) {
    int t = blockIdx.x * 256 + threadIdx.x;
    if (t >= nimg * HP * WP) return;
    int x = t % WP, y = (t / WP) % HP;
    if (y >= 1 && y < 1 + H && x >= 1 && x < 1 + W) return;
    uint4 z4; z4.x = 0; z4.y = 0; z4.z = 0; z4.w = 0;
    uint4* p = (uint4*)(buf + (size_t)t * C);
    #pragma unroll
    for (int i = 0; i < C / 8; ++i) p[i] = z4;
}

// ---- weight prep: deconv (CI,CO,4,4) fp32 -> bf16 [cls][oc][t*CI+ic] ----
template<int CI, int CO>
__global__ __launch_bounds__(256) void wt_deconv(const float* __restrict__ w,
        u16* __restrict__ wb) {
    int i = blockIdx.x * 256 + threadIdx.x;
    if (i >= 4 * CO * 4 * CI) return;
    int ic  = i % CI;
    int t   = (i / CI) & 3;
    int oc  = (i / (CI * 4)) % CO;
    int cls = i / (CI * 4 * CO);
    int py = cls >> 1, px = cls & 1, ty = t >> 1, tx = t & 1;
    int ky = py ? (ty ? 0 : 2) : (ty ? 3 : 1);
    int kx = px ? (tx ? 0 : 2) : (tx ? 3 : 1);
    wb[i] = f2bf(w[(((size_t)ic * CO + oc) * 4 + ky) * 4 + kx]);
}

// ---- weight prep: conv2 (64,32,4,4) fp32 -> bf16 [oc][tap*32+ic] ----
__global__ __launch_bounds__(256) void wt_conv2(const float* __restrict__ w,
        u16* __restrict__ wb) {
    int i = blockIdx.x * 256 + threadIdx.x;
    if (i >= 64 * 512) return;
    int ic = i & 31;
    int k  = (i >> 5) & 15;
    int oc = i >> 9;
    wb[i] = f2bf(w[(size_t)(oc * 32 + ic) * 16 + k]);
}

// ---- weight prep: conv3 (3,32,3,3) fp32 -> bf16 [oc16][tap*32+ic] ----
__global__ __launch_bounds__(256) void wt_conv3(const float* __restrict__ w,
        u16* __restrict__ wk) {
    int i = blockIdx.x * 256 + threadIdx.x;
    if (i >= 16 * 288) return;
    int ic = i & 31;
    int k  = (i / 32) % 9;
    int oc = i / 288;
    float v = 0.f;
    if (oc < 3) v = w[(size_t)(oc * 32 + ic) * 9 + k];
    wk[i] = f2bf(v);
}

// ---- emb prep: fp32 (512,64) -> split-bf16 tables ehi/elo [e][c] ----
__global__ __launch_bounds__(256) void wt_emb(const float* __restrict__ emb,
        u16* __restrict__ ehi, u16* __restrict__ elo) {
    int i = blockIdx.x * 256 + threadIdx.x;      // 32768
    float v = emb[i];
    u16 h = f2bf(v);
    ehi[i] = h;
    elo[i] = f2bf(v - bf2f(h));
}

// ---- conv1: 3->32, k4 s2 p1, ReLU; out = NHWC bf16 padded (131x131) ----
__global__ __launch_bounds__(256) void conv1_kernel(const float* __restrict__ x,
        const float* __restrict__ w, const float* __restrict__ bias,
        u16* __restrict__ out) {
    int t = blockIdx.x * 256 + threadIdx.x;           // 32*128*128
    int ox = t & (W1 - 1);
    int oy = (t >> 7) & (H1 - 1);
    int b  = t >> 14;
    const float* xb = x + (size_t)b * (C_IN * H0 * W0);
    float v[48];
    #pragma unroll
    for (int ic = 0; ic < 3; ++ic)
        #pragma unroll
        for (int dy = 0; dy < 4; ++dy) {
            int iy = oy * 2 - 1 + dy;
            #pragma unroll
            for (int dx = 0; dx < 4; ++dx) {
                int ix = ox * 2 - 1 + dx;
                float val = 0.f;
                if ((unsigned)iy < H0 && (unsigned)ix < W0)
                    val = xb[((size_t)ic * H0 + iy) * W0 + ix];
                v[(ic * 4 + dy) * 4 + dx] = val;
            }
        }
    u16 h[32];
    #pragma unroll
    for (int oc = 0; oc < C1; ++oc) {
        float a = bias[oc];
        #pragma unroll
        for (int k = 0; k < 48; ++k) a = fmaf(v[k], w[oc * 48 + k], a);
        h[oc] = f2bf(fmaxf(a, 0.f));
    }
    uint4* dst = (uint4*)(out + ((size_t)(b * 131 + oy + 1) * 131 + ox + 1) * 32);
    #pragma unroll
    for (int i = 0; i < 4; ++i) {
        uint4 u;
        u.x = (uint)h[i*8+0] | ((uint)h[i*8+1] << 16);
        u.y = (uint)h[i*8+2] | ((uint)h[i*8+3] << 16);
        u.z = (uint)h[i*8+4] | ((uint)h[i*8+5] << 16);
        u.w = (uint)h[i*8+6] | ((uint)h[i*8+7] << 16);
        dst[i] = u;
    }
}

// ---- conv2 via MFMA + LDS weights: 32->64 k4 s2; oc-half in bit 3 (XCD) ----
__global__ __launch_bounds__(256) void conv2_mfma(const u16* __restrict__ z1p,
        const u16* __restrict__ wb, const float* __restrict__ bias,
        float* __restrict__ z) {
    __shared__ u16 wlds[32 * 512];                    // 32 KB: 32 oc x 512 K
    int xcd = blockIdx.x & 7;
    int oh  = (blockIdx.x >> 3) & 1;
    int bx  = (blockIdx.x >> 4) * 8 + xcd;
    for (int j = threadIdx.x; j < 2048; j += 256) {   // 2048 x 16B
        int u = j * 8;
        int byteoff = swz<10>(u * 2);
        *(uint4*)((char*)wlds + byteoff) =
            *(const uint4*)(wb + (size_t)(oh * 32) * 512 + u);
    }
    __syncthreads();
    int wid = threadIdx.x >> 6, lane = threadIdx.x & 63;
    int m0 = bx * 128 + wid * 32;                     // 32 pixels per wave
    int b  = m0 >> 12;
    int y  = (m0 >> 6) & 63;
    int x0 = m0 & 63;
    int l15 = lane & 15, lk = lane >> 4;
    f32x4 acc[2][2] = {};
    int xA = x0 + l15, xB = x0 + 16 + l15;
    for (int ks = 0; ks < 16; ++ks) {
        int dy = ks >> 2, dx = ks & 3;
        int rb = (b * 131 + 2 * y + dy) * 131;
        short8 fbA = *(const short8*)(z1p + ((size_t)(rb + 2 * xA + dx)) * 32 + lk * 8);
        short8 fbB = *(const short8*)(z1p + ((size_t)(rb + 2 * xB + dx)) * 32 + lk * 8);
        #pragma unroll
        for (int f = 0; f < 2; ++f) {
            int byteoff = swz<10>((f * 16 + l15) * 1024 + ks * 64 + lk * 16);
            short8 fa = *(const short8*)((const char*)wlds + byteoff);
            acc[0][f] = mfma16(fa, fbA, acc[0][f]);
            acc[1][f] = mfma16(fa, fbB, acc[1][f]);
        }
    }
    #pragma unroll
    for (int p = 0; p < 2; ++p) {
        int pix = m0 + p * 16 + l15;
        #pragma unroll
        for (int f = 0; f < 2; ++f) {
            int oc0 = oh * 32 + f * 16 + lk * 4;
            float4 bi = *(const float4*)(bias + oc0);
            float4 r;
            r.x = fmaxf(acc[p][f][0] + bi.x, 0.f);
            r.y = fmaxf(acc[p][f][1] + bi.y, 0.f);
            r.z = fmaxf(acc[p][f][2] + bi.z, 0.f);
            r.w = fmaxf(acc[p][f][3] + bi.w, 0.f);
            *(float4*)(z + (size_t)pix * 64 + oc0) = r;
        }
    }
}

// ---------------- embedding squared norms ----------------
__global__ void e2_kernel(const float* __restrict__ emb, float* __restrict__ e2) {
    int e = blockIdx.x * 64 + threadIdx.x;
    float s = 0.f;
    #pragma unroll
    for (int c = 0; c < E_DIM; ++c) {
        float v = emb[(size_t)e * E_DIM + c];
        s = fmaf(v, v, s);
    }
    e2[e] = s;
}

// ---- VQ via MFMA (split-bf16); gather writes BOTH q (fp32 flat) and
// dq (bf16 NHWC padded 66x66) — q_transpose fused away. ----
__global__ __launch_bounds__(256) void vq_mfma(const float* __restrict__ zf,
        const u16* __restrict__ ehi, const u16* __restrict__ elo,
        const float* __restrict__ e2, const float* __restrict__ emb,
        float* __restrict__ q, u16* __restrict__ dq) {
    int wid = threadIdx.x >> 6, lane = threadIdx.x & 63;
    int l15 = lane & 15, lk = lane >> 4;
    int m0 = (blockIdx.x * 4 + wid) * 32;
    short8 zh[2][2], zl[2][2];                 // [half][ks]
    #pragma unroll
    for (int h = 0; h < 2; ++h) {
        int px = m0 + h * 16 + l15;
        const float4* zp = (const float4*)(zf + (size_t)px * 64);
        #pragma unroll
        for (int ks = 0; ks < 2; ++ks) {
            short8 hh, ll;
            #pragma unroll
            for (int j2 = 0; j2 < 2; ++j2) {
                float4 v4 = zp[ks * 8 + lk * 2 + j2];
                float vv[4] = {v4.x, v4.y, v4.z, v4.w};
                #pragma unroll
                for (int j = 0; j < 4; ++j) {
                    u16 hb = f2bf(vv[j]);
                    hh[j2 * 4 + j] = (short)hb;
                    ll[j2 * 4 + j] = (short)f2bf(vv[j] - bf2f(hb));
                }
            }
            zh[h][ks] = hh;
            zl[h][ks] = ll;
        }
    }
    float bs[2] = {3.4e38f, 3.4e38f};
    int   bi[2] = {0, 0};
    for (int tile = 0; tile < 32; ++tile) {
        short8 fh[2], fl[2];
        #pragma unroll
        for (int ks = 0; ks < 2; ++ks) {
            fh[ks] = *(const short8*)(ehi + (size_t)(tile * 16 + l15) * 64 + ks * 32 + lk * 8);
            fl[ks] = *(const short8*)(elo + (size_t)(tile * 16 + l15) * 64 + ks * 32 + lk * 8);
        }
        float4 e2v = *(const float4*)(e2 + tile * 16 + lk * 4);
        float ee[4] = {e2v.x, e2v.y, e2v.z, e2v.w};
        #pragma unroll
        for (int h = 0; h < 2; ++h) {
            f32x4 acc = {};
            #pragma unroll
            for (int ks = 0; ks < 2; ++ks) {
                acc = mfma16(fh[ks], zh[h][ks], acc);
                acc = mfma16(fl[ks], zh[h][ks], acc);
                acc = mfma16(fh[ks], zl[h][ks], acc);
            }
            #pragma unroll
            for (int r = 0; r < 4; ++r) {
                float sc = ee[r] - 2.f * acc[r];
                int ei = tile * 16 + lk * 4 + r;
                if (sc < bs[h]) { bs[h] = sc; bi[h] = ei; }
            }
        }
    }
    #pragma unroll
    for (int h = 0; h < 2; ++h) {
        #pragma unroll
        for (int off = 16; off < 64; off <<= 1) {
            float s2 = __shfl_xor(bs[h], off, 64);
            int   i2 = __shfl_xor(bi[h], off, 64);
            if (s2 < bs[h] || (s2 == bs[h] && i2 < bi[h])) { bs[h] = s2; bi[h] = i2; }
        }
    }
    #pragma unroll
    for (int h = 0; h < 2; ++h) {
        for (int p = 0; p < 16; ++p) {
            int idx = __shfl(bi[h], p, 64);
            int px  = m0 + h * 16 + p;
            float val = emb[(size_t)idx * 64 + lane];
            q[(size_t)px * 64 + lane] = val;
            int xx = px & 63, yy = (px >> 6) & 63, bb = px >> 12;
            dq[((size_t)(bb * 66 + yy + 1) * 66 + xx + 1) * 64 + lane] = f2bf(val);
        }
    }
}

// ---- loss with faithful NCHW pairing: q_flat[i] vs z_nchw(i); z stored NHWC ----
__global__ __launch_bounds__(256) void loss_tr(const float* __restrict__ q,
        const float* __restrict__ z, float* __restrict__ part) {
    __shared__ float zt[64 * 65];
    int bh = blockIdx.x;                       // b*64 + h
    size_t zbase = (size_t)bh * 4096;
    for (int j = threadIdx.x; j < 4096; j += 256) {
        int w = j >> 6, c = j & 63;
        zt[w * 65 + c] = z[zbase + j];
    }
    __syncthreads();
    int b = bh >> 6, h = bh & 63;
    int w = threadIdx.x & 63;
    float s = 0.f;
    #pragma unroll
    for (int k = 0; k < 16; ++k) {
        int cc = (threadIdx.x >> 6) + k * 4;
        float qv = q[(size_t)b * 262144 + (size_t)cc * 4096 + h * 64 + w];
        float d = qv - zt[w * 65 + cc];
        s = fmaf(d, d, s);
    }
    #pragma unroll
    for (int off = 32; off; off >>= 1) s += __shfl_down(s, off, 64);
    __shared__ float red[4];
    int lane = threadIdx.x & 63, wid = threadIdx.x >> 6;
    if (lane == 0) red[wid] = s;
    __syncthreads();
    if (threadIdx.x == 0) part[blockIdx.x] = (red[0] + red[1]) + (red[2] + red[3]);
}

__global__ __launch_bounds__(256) void loss_final(const float* __restrict__ part,
        float* __restrict__ loss, float scale) {
    float s = 0.f;
    for (int i = threadIdx.x; i < 2048; i += 256) s += part[i];
    #pragma unroll
    for (int off = 32; off; off >>= 1) s += __shfl_down(s, off, 64);
    __shared__ float red[4];
    int lane = threadIdx.x & 63, wid = threadIdx.x >> 6;
    if (lane == 0) red[wid] = s;
    __syncthreads();
    if (threadIdx.x == 0)
        *loss = ((red[0] + red[1]) + (red[2] + red[3])) * scale;
}

// ---- deconv1 (64->64, 64x64) LDS-staged: block = (b, row-pair, py, oh) ----
__global__ __launch_bounds__(512) void deconv1_stage(const u16* __restrict__ in,
        const u16* __restrict__ wb, const float* __restrict__ bias,
        u16* __restrict__ out) {
    __shared__ u16 wlds[2 * 32 * 256];         // 32 KB
    __shared__ u16 ilds[3 * 66 * 64];          // 25,344 B
    int xcd = blockIdx.x & 7;
    int pv  = (blockIdx.x >> 3) & 3;
    int bx  = (blockIdx.x >> 5) * 8 + xcd;     // 0..1023 = b*32 + ry
    int py = pv & 1;
    int oh = pv >> 1;
    int b  = bx >> 5;
    int y0 = (bx & 31) * 2;                    // output row pair y0, y0+1
    for (int j = threadIdx.x; j < 2048; j += 512) {
        int u = j * 8;
        int clsl = u >> 13;
        int rem = u & 8191;
        *(uint4*)((char*)wlds + swz<9>(u * 2)) = *(const uint4*)(wb
            + ((size_t)((py * 2 + clsl) * 64 + oh * 32)) * 256 + rem);
    }
    int rows_start = y0 - 1 + py;
    for (int j = threadIdx.x; j < 1584; j += 512) {
        int rr = j / 528;
        int rem = j - rr * 528;
        int px = rem >> 3, c16 = rem & 7;
        uint4 v = *(const uint4*)(in
            + ((size_t)(b * 66 + rows_start + 1 + rr) * 66 + px) * 64 + c16 * 8);
        int lbyte = (j * 16) ^ ((px & 7) << 4);
        *(uint4*)((char*)ilds + lbyte) = v;
    }
    __syncthreads();

    int wid = threadIdx.x >> 6, lane = threadIdx.x & 63;
    int l15 = lane & 15, lk = lane >> 4;
    int pxb = wid * 16;                        // local px 0..127 over 2 rows
    int r   = pxb >> 6;                        // output row within pair
    int xw  = pxb & 63;
    int y   = y0 + r;
    f32x4 acc[2][2] = {};                      // [pxc][f]
    #pragma unroll
    for (int idy = 0; idy < 2; ++idy) {
        int rr = r + (idy ? py : (1 - py));    // stage row index for this tap
        #pragma unroll
        for (int idx = 0; idx < 3; ++idx) {
            int dx = idx - 1;
            #pragma unroll
            for (int ks = 0; ks < 2; ++ks) {
                int pxl = xw + l15 + idx;      // padded col 0..65
                int lbyte = ((rr * 66 + pxl) * 128 + ks * 64 + lk * 16)
                            ^ ((pxl & 7) << 4);
                short8 fb = *(const short8*)((const char*)ilds + lbyte);
                #pragma unroll
                for (int pxc = 0; pxc < 2; ++pxc) {
                    int sx = pxc ? 1 : -1;
                    if (!(dx == 0 || dx == sx)) continue;
                    int t = 2 * (idy != 0) + (dx != 0);
                    #pragma unroll
                    for (int f = 0; f < 2; ++f) {
                        int row = pxc * 32 + f * 16 + l15;
                        int byteoff = swz<9>(row * 512 + (t * 2 + ks) * 64 + lk * 16);
                        short8 fa = *(const short8*)((const char*)wlds + byteoff);
                        acc[pxc][f] = mfma16(fa, fb, acc[pxc][f]);
                    }
                }
            }
        }
    }

    int x = xw + l15;
    #pragma unroll
    for (int pxc = 0; pxc < 2; ++pxc) {
        int oy = 2 * y + py + 1, ox = 2 * x + pxc + 1;
        size_t po = ((size_t)(b * 130 + oy) * 130 + ox) * 64;
        #pragma unroll
        for (int f = 0; f < 2; ++f) {
            int oc0 = oh * 32 + f * 16 + lk * 4;
            float4 bi = *(const float4*)(bias + oc0);
            float r0 = fmaxf(acc[pxc][f][0] + bi.x, 0.f);
            float r1 = fmaxf(acc[pxc][f][1] + bi.y, 0.f);
            float r2 = fmaxf(acc[pxc][f][2] + bi.z, 0.f);
            float r3 = fmaxf(acc[pxc][f][3] + bi.w, 0.f);
            uint2 uu;
            uu.x = (uint)f2bf(r0) | ((uint)f2bf(r1) << 16);
            uu.y = (uint)f2bf(r2) | ((uint)f2bf(r3) << 16);
            *(uint2*)(out + po + oc0) = uu;
        }
    }
}

// ---- deconv2 (64->32, 128x128): input LDS + weight LDS, 512 threads ----
__global__ __launch_bounds__(512) void deconv2_stage(const u16* __restrict__ in,
        const u16* __restrict__ wb, const float* __restrict__ bias,
        u16* __restrict__ out) {
    __shared__ u16 wlds[2 * 32 * 256];         // 32 KB
    __shared__ u16 ilds[2 * 130 * 64];         // 33,280 B
    int xcd = blockIdx.x & 7;
    int py  = (blockIdx.x >> 3) & 1;
    int bx  = (blockIdx.x >> 4) * 8 + xcd;     // 0..4095 = b*128 + y
    int b = bx >> 7;
    int y = bx & 127;
    int sy = py ? 1 : -1;
    for (int j = threadIdx.x; j < 2048; j += 512) {
        int u = j * 8;
        int clsl = u >> 13;
        int rem = u & 8191;
        *(uint4*)((char*)wlds + swz<9>(u * 2)) = *(const uint4*)(wb
            + ((size_t)(py * 2 + clsl) * 32) * 256 + rem);
    }
    int rowg0 = (b * 130 + y + 1) * 130;
    int rowg1 = (b * 130 + y + sy + 1) * 130;
    for (int j = threadIdx.x; j < 2080; j += 512) {
        int row = (j >= 1040);
        int rem = j - row * 1040;
        int px = rem >> 3, c16 = rem & 7;
        int rg = row ? rowg1 : rowg0;
        uint4 v = *(const uint4*)(in + (size_t)(rg + px) * 64 + c16 * 8);
        int lbyte = (j * 16) ^ ((px & 7) << 4);
        *(uint4*)((char*)ilds + lbyte) = v;
    }
    __syncthreads();

    int wid = threadIdx.x >> 6, lane = threadIdx.x & 63;
    int l15 = lane & 15, lk = lane >> 4;
    int xw = wid * 16;
    f32x4 acc[2][2] = {};                      // [pxc][f]
    #pragma unroll
    for (int idy = 0; idy < 2; ++idy)
        #pragma unroll
        for (int idx = 0; idx < 3; ++idx) {
            int dx = idx - 1;
            #pragma unroll
            for (int ks = 0; ks < 2; ++ks) {
                int pxl = xw + l15 + idx;
                int lbyte = ((idy * 130 + pxl) * 128 + ks * 64 + lk * 16)
                            ^ ((pxl & 7) << 4);
                short8 fb = *(const short8*)((const char*)ilds + lbyte);
                #pragma unroll
                for (int pxc = 0; pxc < 2; ++pxc) {
                    int sx = pxc ? 1 : -1;
                    if (!(dx == 0 || dx == sx)) continue;
                    int t = 2 * (idy != 0) + (dx != 0);
                    #pragma unroll
                    for (int f = 0; f < 2; ++f) {
                        int row = pxc * 32 + f * 16 + l15;
                        int byteoff = swz<9>(row * 512 + (t * 2 + ks) * 64 + lk * 16);
                        short8 fa = *(const short8*)((const char*)wlds + byteoff);
                        acc[pxc][f] = mfma16(fa, fb, acc[pxc][f]);
                    }
                }
            }
        }

    int x = xw + l15;
    #pragma unroll
    for (int pxc = 0; pxc < 2; ++pxc) {
        int oy = 2 * y + py + 1, ox = 2 * x + pxc + 1;
        size_t po = ((size_t)(b * 258 + oy) * 258 + ox) * 32;
        #pragma unroll
        for (int f = 0; f < 2; ++f) {
            int oc0 = f * 16 + lk * 4;
            float4 bi = *(const float4*)(bias + oc0);
            float r0 = fmaxf(acc[pxc][f][0] + bi.x, 0.f);
            float r1 = fmaxf(acc[pxc][f][1] + bi.y, 0.f);
            float r2 = fmaxf(acc[pxc][f][2] + bi.z, 0.f);
            float r3 = fmaxf(acc[pxc][f][3] + bi.w, 0.f);
            uint2 uu;
            uu.x = (uint)f2bf(r0) | ((uint)f2bf(r1) << 16);
            uu.y = (uint)f2bf(r2) | ((uint)f2bf(r3) << 16);
            *(uint2*)(out + po + oc0) = uu;
        }
    }
}

// ---- conv3 via MFMA: 32->3 k3 s1 p1 + sigmoid; bf16 weights (no split),
// 32 px/wave: fa reads amortized over both px-halves. ----
__global__ __launch_bounds__(256) void conv3_mfma(const u16* __restrict__ in,
        const u16* __restrict__ wk, const float* __restrict__ bias,
        float* __restrict__ out) {
    __shared__ u16 walds[16 * 288];            // 9216 B, swizzled
    for (int j = threadIdx.x; j < 576; j += 256) {
        int u = j * 8;
        if (u < 16 * 288)
            *(uint4*)((char*)walds + swz<9>(u * 2)) = *(const uint4*)(wk + u);
    }
    __syncthreads();
    int wid = threadIdx.x >> 6, lane = threadIdx.x & 63;
    int m0 = (blockIdx.x * 4 + wid) * 32;      // 32 px per wave
    int b   = m0 >> 16;
    int rem = m0 & 65535;
    int y   = rem >> 8;
    int x0  = rem & 255;
    int l15 = lane & 15, lk = lane >> 4;
    short8 fb[3][3][2];
    #pragma unroll
    for (int dy = 0; dy < 3; ++dy) {
        int rb = (b * 258 + y + dy) * 258;
        #pragma unroll
        for (int dx = 0; dx < 3; ++dx)
            #pragma unroll
            for (int p = 0; p < 2; ++p)
                fb[dy][dx][p] = *(const short8*)(in
                    + (size_t)(rb + x0 + p * 16 + l15 + dx) * 32 + lk * 8);
    }
    f32x4 acc[2] = {};
    #pragma unroll
    for (int ks = 0; ks < 9; ++ks) {
        int base = (l15 * 288 + ks * 32 + lk * 8) * 2;
        short8 fa = *(const short8*)((const char*)walds + swz<9>(base));
        acc[0] = mfma16(fa, fb[ks / 3][ks % 3][0], acc[0]);
        acc[1] = mfma16(fa, fb[ks / 3][ks % 3][1], acc[1]);
    }
    if (lk == 0) {
        #pragma unroll
        for (int p = 0; p < 2; ++p) {
            int px = x0 + p * 16 + l15;
            float* ob = out + (size_t)b * 196608 + (size_t)y * 256 + px;
            ob[0]      = 1.f / (1.f + expf(-(acc[p][0] + bias[0])));
            ob[65536]  = 1.f / (1.f + expf(-(acc[p][1] + bias[1])));
            ob[131072] = 1.f / (1.f + expf(-(acc[p][2] + bias[2])));
        }
    }
}

// ---------------- launch ----------------
extern "C" void kernel_launch(void* const* d_in, const int* in_sizes, int n_in,
                              void* d_out, int out_size, void* d_ws, size_t ws_size,
                              hipStream_t stream) {
    (void)in_sizes; (void)n_in; (void)out_size;
    const float* x   = (const float*)d_in[0];
    const float* e1w = (const float*)d_in[1];
    const float* e1b = (const float*)d_in[2];
    const float* e2w = (const float*)d_in[3];
    const float* e2b = (const float*)d_in[4];
    const float* emb = (const float*)d_in[5];
    const float* d1w = (const float*)d_in[6];
    const float* d1b = (const float*)d_in[7];
    const float* d2w = (const float*)d_in[8];
    const float* d2b = (const float*)d_in[9];
    const float* d3w = (const float*)d_in[10];
    const float* d3b = (const float*)d_in[11];

    float* out   = (float*)d_out;
    float* recon = out;                    // 6291456 floats
    float* loss  = out + 6291456;          // 1 float
    float* q     = out + 6291457;          // 8388608 floats (4B-aligned only)

    char* wsb = (char*)d_ws;
    u16*   wt1b = (u16*)(wsb + 0);         // 131072 B
    u16*   wt2b = (u16*)(wsb + 131072);    // 65536 B
    u16*   wc2b = (u16*)(wsb + 196608);    // 65536 B
    float* e2v  = (float*)(wsb + 262144);  // 512 f
    float* prt  = (float*)(wsb + 264192);  // 2048 f -> ends 272384
    u16*   wk3  = (u16*)(wsb + 272384);    // 9216 B -> ends 281600
    u16*   ehib = (u16*)(wsb + 290816);    // 65536 B
    u16*   elob = (u16*)(wsb + 356352);    // 65536 B -> ends 421888
    char*  big  = wsb + 524288;

    u16*   z1p = (u16*)big;                     // 35,145,728 B
    float* zf  = (float*)(big + 35145728);      // 33,554,432 B
    u16* dq = (u16*)big;                        // decoder reuse (z1p dead after conv2)

    size_t avail = ws_size > (size_t)524288 ? ws_size - 524288 : 0;
    int G = 32;
    while (G > 1 && (size_t)17842176 + (size_t)G * 6423296 > avail) G >>= 1;
    int ngrp = BB / G;
    u16* h1p = (u16*)(big + 17842176);
    u16* h2p = (u16*)(big + 17842176 + (size_t)G * 2163200);

    // weight prep
    wt_deconv<64, 64><<<256, 256, 0, stream>>>(d1w, wt1b);
    wt_deconv<64, 32><<<128, 256, 0, stream>>>(d2w, wt2b);
    wt_conv2<<<128, 256, 0, stream>>>(e2w, wc2b);
    wt_conv3<<<18, 256, 0, stream>>>(d3w, wk3);
    wt_emb<<<128, 256, 0, stream>>>(emb, ehib, elob);
    e2_kernel<<<8, 64, 0, stream>>>(emb, e2v);

    // encoder (full batch)
    border_zero<32, 131, 131, 128, 128><<<2146, 256, 0, stream>>>(z1p, 32);
    conv1_kernel<<<2048, 256, 0, stream>>>(x, e1w, e1b, z1p);
    conv2_mfma<<<2048, 256, 0, stream>>>(z1p, wc2b, e2b, zf);
    // z1p dead now; dq aliases it — zero its border, then vq writes q AND dq
    border_zero<64, 66, 66, 64, 64><<<545, 256, 0, stream>>>(dq, 32);
    vq_mfma<<<1024, 256, 0, stream>>>(zf, ehib, elob, e2v, emb, q, dq);
    loss_tr<<<2048, 256, 0, stream>>>(q, zf, prt);

    // decoder
    border_zero<64, 130, 130, 128, 128><<<(G * 16900 + 255) / 256, 256, 0, stream>>>(h1p, G);
    border_zero<32, 258, 258, 256, 256><<<(G * 66564 + 255) / 256, 256, 0, stream>>>(h2p, G);
    for (int g = 0; g < ngrp; ++g) {
        u16* dqg = dq + (size_t)g * G * 278784;
        // deconv1: LDS-staged, (py,oh) in bits 3-4, 512 threads
        deconv1_stage<<<G * 32 * 4, 512, 0, stream>>>(dqg, wt1b, d1b, h1p);
        // deconv2: LDS-staged, py in bit 3, 512 threads
        deconv2_stage<<<G * 128 * 2, 512, 0, stream>>>(h1p, wt2b, d2b, h2p);
        // conv3: 32 px/wave, hi-only weights
        conv3_mfma<<<G * 512, 256, 0, stream>>>(h2p, wk3, d3b,
                                                recon + (size_t)g * G * 196608);
    }
    loss_final<<<1, 256, 0, stream>>>(prt, loss, 1.25f / (float)NZ);
}